// Round 6
// baseline (1232.428 us; speedup 1.0000x reference)
//
#include <hip/hip_runtime.h>
#include <math.h>

#define B 2
#define N1 1024
#define N2 2048
#define SLOPE 0.2f
#define QG 8          // queries per ball task
#define NBLK 768      // 3 blocks/CU x 256 CU -- co-resident by construction

typedef short bf16x8 __attribute__((ext_vector_type(8)));
typedef float f32x4 __attribute__((ext_vector_type(4)));
typedef unsigned short u16x4 __attribute__((ext_vector_type(4)));
typedef unsigned short u16x8 __attribute__((ext_vector_type(8)));

__device__ __forceinline__ unsigned short f2bf(float x) {
    unsigned int u = __float_as_uint(x);
    unsigned int r = (u + 0x7fffu + ((u >> 16) & 1u)) >> 16;   // RNE
    return (unsigned short)r;
}
__device__ __forceinline__ float bf2f(unsigned short h) {
    return __uint_as_float(((unsigned int)h) << 16);
}
__device__ __forceinline__ unsigned fenc(float f) {
    unsigned u = __float_as_uint(f);
    return (u & 0x80000000u) ? ~u : (u | 0x80000000u);
}
__device__ __forceinline__ float fdec(unsigned u) {
    unsigned b = (u & 0x80000000u) ? (u & 0x7FFFFFFFu) : ~u;
    return __uint_as_float(b);
}

// ---- ws byte offsets ----
#define OFF_WP     0
#define OFF_X1P    6291456
#define OFF_XMP    18874368
#define OFF_X2P    31457280
#define OFF_X3P    39845888
#define OFF_X4P    44040192
#define OFF_C1     48234496
#define OFF_GLOBE  48238592
#define OFF_GBIAS  48242688
#define OFF_HACC1  48246784   // [6144][4] f32
#define OFF_HACC2  48345088   // [4096][4] f32
#define OFF_CNT    48410624   // grid-barrier counter (zeroed by hipMemsetAsync)
#define ZERO_WORDS 43008      // globE..hacc2 end

// ---- device-wide barrier: monotone counter, all 768 blocks resident ----
// Bailout cap: a logic error fails the numeric check instead of hanging the GPU.
__device__ __forceinline__ void gridbar(unsigned* cnt, unsigned target) {
    __syncthreads();
    if (threadIdx.x == 0) {
        __threadfence();   // release our phase's writes (device scope)
        __hip_atomic_fetch_add(cnt, 1u, __ATOMIC_ACQ_REL, __HIP_MEMORY_SCOPE_AGENT);
        long it = 0;
        while (__hip_atomic_load(cnt, __ATOMIC_ACQUIRE, __HIP_MEMORY_SCOPE_AGENT) < target) {
            __builtin_amdgcn_s_sleep(1);
            if (++it > 5000000L) break;    // fail visibly, never hang
        }
        __threadfence();   // acquire: invalidate L1 before next phase's reads
    }
    __syncthreads();
}

// ---------------- GEMM tile: TERMS=3 split-bf16, TERMS=1 plain bf16 ----------------
template<int TERMS>
__device__ __forceinline__ void gemm_tile(
    char* sm, int t, int nb0, int ob0,
    const unsigned short* __restrict__ Wp, int ldw,
    const unsigned short* __restrict__ Xp, int ldx,
    int K,
    const float* __restrict__ bias, int bias_div,
    unsigned short* __restrict__ Xn, int ldxn, int lo_off, int row_off, int pack_min,
    const float* __restrict__ Wx, float* __restrict__ hacc,
    unsigned* __restrict__ globE, int glob_min) {

    constexpr int NBUF  = (TERMS == 3) ? 1 : 2;
    constexpr int BUFSZ = (TERMS == 3) ? 32768 : 16384;
    constexpr int XBASE = (TERMS == 3) ? 16384 : 8192;

    const unsigned short* gp[8];
    int lo_[8];
    #pragma unroll
    for (int p = 0; p < 8; ++p) {
        const int T = p >> 1;
        if (TERMS == 1 && (T == 1 || T == 3)) continue;
        int j2 = ((p & 1) << 8) + t;
        int r = j2 >> 3, cl = j2 & 7, cs = cl ^ (r & 7);
        gp[p] = (T < 2)
            ? (Wp + (long)(ob0 + r) * ldw + ((T == 1) ? K : 0) + cs * 8)
            : (Xp + (long)(nb0 + r) * ldx + ((T == 3) ? K : 0) + cs * 8);
        const int reg = (TERMS == 3) ? p : ((p < 2) ? p : p - 2);
        lo_[p] = reg * 4096 + t * 16;
    }

    const int lane = t & 63, w = t >> 6;
    const int wy = w >> 1, wx = w & 1;
    const int quad = lane >> 4, l15 = lane & 15;
    const int xm = l15 & 7;
    const int rowA = (wy * 32 + l15) * 128;
    const int rowB = (wx * 32 + l15) * 128;
    const int ca0 = (quad ^ xm) * 16;
    const int ca1 = ((quad + 4) ^ xm) * 16;

    f32x4 acc[2][2];
    #pragma unroll
    for (int i = 0; i < 2; ++i)
        #pragma unroll
        for (int j = 0; j < 2; ++j) { f32x4 zz = {0.f, 0.f, 0.f, 0.f}; acc[i][j] = zz; }

    auto stage = [&](int buf, int k0) {
        #pragma unroll
        for (int p = 0; p < 8; ++p) {
            const int T = p >> 1;
            if (TERMS == 1 && (T == 1 || T == 3)) continue;
            __builtin_amdgcn_global_load_lds(
                (const __attribute__((address_space(1))) void*)(const void*)(gp[p] + k0),
                (__attribute__((address_space(3))) void*)(void*)(sm + buf * BUFSZ + lo_[p]),
                16, 0, 0);
        }
    };

    auto compute = [&](int buf) {
        char* smb = sm + buf * BUFSZ;
        #pragma unroll
        for (int sub = 0; sub < 2; ++sub) {
            const int cb = (sub == 0) ? ca0 : ca1;
            bf16x8 ah[2], bh[2];
            #pragma unroll
            for (int i = 0; i < 2; ++i)
                ah[i] = *(const bf16x8*)(const void*)(smb + rowA + i * 2048 + cb);
            #pragma unroll
            for (int j = 0; j < 2; ++j)
                bh[j] = *(const bf16x8*)(const void*)(smb + XBASE + rowB + j * 2048 + cb);
            if (TERMS == 3) {
                bf16x8 al[2], bl[2];
                #pragma unroll
                for (int i = 0; i < 2; ++i)
                    al[i] = *(const bf16x8*)(const void*)(smb + 8192 + rowA + i * 2048 + cb);
                #pragma unroll
                for (int j = 0; j < 2; ++j)
                    bl[j] = *(const bf16x8*)(const void*)(smb + 24576 + rowB + j * 2048 + cb);
                #pragma unroll
                for (int i = 0; i < 2; ++i)
                    #pragma unroll
                    for (int j = 0; j < 2; ++j) {
                        acc[i][j] = __builtin_amdgcn_mfma_f32_16x16x32_bf16(ah[i], bh[j], acc[i][j], 0, 0, 0);
                        acc[i][j] = __builtin_amdgcn_mfma_f32_16x16x32_bf16(ah[i], bl[j], acc[i][j], 0, 0, 0);
                        acc[i][j] = __builtin_amdgcn_mfma_f32_16x16x32_bf16(al[i], bh[j], acc[i][j], 0, 0, 0);
                    }
            } else {
                #pragma unroll
                for (int i = 0; i < 2; ++i)
                    #pragma unroll
                    for (int j = 0; j < 2; ++j)
                        acc[i][j] = __builtin_amdgcn_mfma_f32_16x16x32_bf16(ah[i], bh[j], acc[i][j], 0, 0, 0);
            }
        }
    };

    if constexpr (TERMS == 3) {
        for (int k0 = 0; k0 < K; k0 += 64) {
            stage(0, k0);
            __syncthreads();
            compute(0);
            __syncthreads();
        }
    } else {
        stage(0, 0);
        __syncthreads();
        int cur = 0;
        for (int k0 = 64; k0 < K; k0 += 64) {
            stage(cur ^ 1, k0);
            compute(cur);
            __syncthreads();
            cur ^= 1;
        }
        compute(cur);
    }

    // ---- epilogue ----
    float val[2][2][4];
    #pragma unroll
    for (int j = 0; j < 2; ++j) {
        int n = nb0 + wx * 32 + j * 16 + l15;
        int bidx0 = (bias_div >= (1 << 29)) ? 0 : (n / bias_div) * 512;
        #pragma unroll
        for (int i = 0; i < 2; ++i) {
            int ob = ob0 + wy * 32 + i * 16 + quad * 4;
            #pragma unroll
            for (int r = 0; r < 4; ++r) {
                float x = acc[i][j][r] + bias[bidx0 + ob + r];
                val[i][j][r] = (x > 0.f) ? x : SLOPE * x;
            }
        }
        if (Xn && n >= pack_min) {
            long nl = n - row_off;
            #pragma unroll
            for (int i = 0; i < 2; ++i) {
                int ob = ob0 + wy * 32 + i * 16 + quad * 4;
                u16x4 h4;
                #pragma unroll
                for (int r = 0; r < 4; ++r) h4[r] = f2bf(val[i][j][r]);
                *(u16x4*)(void*)(Xn + nl * ldxn + ob) = h4;
                if (lo_off) {
                    u16x4 l4;
                    #pragma unroll
                    for (int r = 0; r < 4; ++r) l4[r] = f2bf(val[i][j][r] - bf2f(h4[r]));
                    *(u16x4*)(void*)(Xn + nl * ldxn + lo_off + ob) = l4;
                }
            }
        }
    }

    if (hacc) {
        __syncthreads();
        float* smh = (float*)sm;                     // [64][4]
        unsigned* smg = (unsigned*)(sm + 1024);      // [64]
        smh[t] = 0.f;
        if (t < 64) smg[t] = 0u;
        __syncthreads();
        float wxv[3][2][4];
        #pragma unroll
        for (int ch = 0; ch < 3; ++ch)
            #pragma unroll
            for (int i = 0; i < 2; ++i)
                #pragma unroll
                for (int r = 0; r < 4; ++r)
                    wxv[ch][i][r] = Wx[ch * 512 + ob0 + wy * 32 + i * 16 + quad * 4 + r];
        #pragma unroll
        for (int j = 0; j < 2; ++j) {
            int nl = wx * 32 + j * 16 + l15;
            float p0 = 0.f, p1 = 0.f, p2 = 0.f;
            #pragma unroll
            for (int i = 0; i < 2; ++i)
                #pragma unroll
                for (int r = 0; r < 4; ++r) {
                    float v = val[i][j][r];
                    p0 += v * wxv[0][i][r];
                    p1 += v * wxv[1][i][r];
                    p2 += v * wxv[2][i][r];
                }
            atomicAdd(&smh[nl * 4 + 0], p0);
            atomicAdd(&smh[nl * 4 + 1], p1);
            atomicAdd(&smh[nl * 4 + 2], p2);
        }
        if (globE && nb0 >= glob_min) {
            #pragma unroll
            for (int i = 0; i < 2; ++i)
                #pragma unroll
                for (int r = 0; r < 4; ++r) {
                    float mx = fmaxf(val[i][0][r], val[i][1][r]);
                    atomicMax(&smg[wy * 32 + i * 16 + quad * 4 + r], fenc(mx));
                }
        }
        __syncthreads();
        if (t < 64) {
            atomicAdd(&hacc[(long)(nb0 + t) * 4 + 0], smh[t * 4 + 0]);
            atomicAdd(&hacc[(long)(nb0 + t) * 4 + 1], smh[t * 4 + 1]);
            atomicAdd(&hacc[(long)(nb0 + t) * 4 + 2], smh[t * 4 + 2]);
            if (globE && nb0 >= glob_min) {
                int b = (nb0 - glob_min) >> 11;
                atomicMax(&globE[b * 512 + ob0 + t], smg[t]);
            }
        }
        __syncthreads();
    }
}

// ---------------- ball task (8 queries): shared scan + union gather-max ----------------
struct BallSm {
    float pts[N2 * 3];          // 24576 B
    unsigned char mark[N2];     // 2048 B
    int wcnt[4][QG];            // 128 B
    int ulist[512];             // 2048 B
    int ucnt;
};
static_assert(sizeof(BallSm) <= 32768, "ball LDS overlay too big");

__device__ __forceinline__ void ball_task(char* smraw, int tid, int i0, int b,
                                          const float* __restrict__ fine,
                                          unsigned short* __restrict__ X2P) {
    BallSm* s = (BallSm*)smraw;
    int lane = tid & 63, wv = tid >> 6;

    const float* fb = fine + (long)b * N2 * 3;
    for (int l = tid; l < N2 * 3; l += 256) s->pts[l] = fb[l];
    *(int*)(void*)&s->mark[tid * 8] = 0;
    *(int*)(void*)&s->mark[tid * 8 + 4] = 0;
    if (tid == 0) s->ucnt = 0;
    __syncthreads();

    float cx[QG], cy[QG], cz[QG], sqc[QG];
    #pragma unroll
    for (int g = 0; g < QG; ++g) {
        cx[g] = s->pts[(i0 + g) * 3 + 0];
        cy[g] = s->pts[(i0 + g) * 3 + 1];
        cz[g] = s->pts[(i0 + g) * 3 + 2];
        sqc[g] = __fadd_rn(__fadd_rn(__fmul_rn(cx[g], cx[g]), __fmul_rn(cy[g], cy[g])),
                           __fmul_rn(cz[g], cz[g]));
    }

    int cnt[QG];
    #pragma unroll
    for (int g = 0; g < QG; ++g) cnt[g] = 0;

    for (int it = 0; it < N2 / 256; ++it) {
        int j = it * 256 + tid;
        float xj = s->pts[j * 3 + 0], yj = s->pts[j * 3 + 1], zj = s->pts[j * 3 + 2];
        float sqj = __fadd_rn(__fadd_rn(__fmul_rn(xj, xj), __fmul_rn(yj, yj)), __fmul_rn(zj, zj));
        unsigned long long bm[QG];
        #pragma unroll
        for (int g = 0; g < QG; ++g) {
            float dot = __fadd_rn(__fadd_rn(__fmul_rn(cx[g], xj), __fmul_rn(cy[g], yj)),
                                  __fmul_rn(cz[g], zj));
            float d2 = __fsub_rn(__fadd_rn(sqc[g], sqj), __fmul_rn(2.0f, dot));
            bm[g] = __ballot(d2 < 0.01f);
        }
        if (lane < QG) s->wcnt[wv][lane] = __popcll(bm[lane]);
        __syncthreads();
        unsigned mybits = 0;
        #pragma unroll
        for (int g = 0; g < QG; ++g) {
            int base = cnt[g];
            #pragma unroll
            for (int q = 0; q < 3; ++q) { if (q < wv) base += s->wcnt[q][g]; }
            int rank = base + __popcll(bm[g] & ((1ull << lane) - 1ull));
            if (((bm[g] >> lane) & 1ull) && rank < 64) mybits |= 1u << g;
            cnt[g] += s->wcnt[0][g] + s->wcnt[1][g] + s->wcnt[2][g] + s->wcnt[3][g];
        }
        s->mark[j] = (unsigned char)mybits;
        bool done = true;
        #pragma unroll
        for (int g = 0; g < QG; ++g) done = done && (cnt[g] >= 64);
        __syncthreads();
        if (done) break;                 // uniform
    }

    for (int it = 0; it < N2 / 256; ++it) {
        int j = it * 256 + tid;
        unsigned mk = s->mark[j];
        if (mk) { int r = atomicAdd(&s->ucnt, 1); s->ulist[r] = j | ((int)mk << 16); }
    }
    __syncthreads();
    int nu = __builtin_amdgcn_readfirstlane(s->ucnt);

    const unsigned short* hb = X2P + (long)b * N2 * 1024;
    float a0[QG], a1[QG];
    #pragma unroll
    for (int g = 0; g < QG; ++g) { a0[g] = -1e30f; a1[g] = -1e30f; }

    auto apply = [&](unsigned mk, unsigned v) {
        float f0 = bf2f((unsigned short)(v & 0xFFFFu));
        float f1 = bf2f((unsigned short)(v >> 16));
        #pragma unroll
        for (int g = 0; g < QG; ++g) {
            if (mk & (1u << g)) {
                a0[g] = fmaxf(a0[g], f0);
                a1[g] = fmaxf(a1[g], f1);
            }
        }
    };

    int u = 0;
    for (; u + 4 <= nu; u += 4) {
        int e0 = __builtin_amdgcn_readfirstlane(s->ulist[u + 0]);
        int e1 = __builtin_amdgcn_readfirstlane(s->ulist[u + 1]);
        int e2 = __builtin_amdgcn_readfirstlane(s->ulist[u + 2]);
        int e3 = __builtin_amdgcn_readfirstlane(s->ulist[u + 3]);
        unsigned v0 = *(const unsigned*)(const void*)(hb + (long)(e0 & 0xFFFF) * 1024 + tid * 2);
        unsigned v1 = *(const unsigned*)(const void*)(hb + (long)(e1 & 0xFFFF) * 1024 + tid * 2);
        unsigned v2 = *(const unsigned*)(const void*)(hb + (long)(e2 & 0xFFFF) * 1024 + tid * 2);
        unsigned v3 = *(const unsigned*)(const void*)(hb + (long)(e3 & 0xFFFF) * 1024 + tid * 2);
        apply(((unsigned)e0) >> 16, v0);
        apply(((unsigned)e1) >> 16, v1);
        apply(((unsigned)e2) >> 16, v2);
        apply(((unsigned)e3) >> 16, v3);
    }
    for (; u < nu; ++u) {
        int e = __builtin_amdgcn_readfirstlane(s->ulist[u]);
        unsigned v = *(const unsigned*)(const void*)(hb + (long)(e & 0xFFFF) * 1024 + tid * 2);
        apply(((unsigned)e) >> 16, v);
    }

    #pragma unroll
    for (int g = 0; g < QG; ++g) {
        unsigned short* orow = X2P + (long)(b * N2 + i0 + g) * 1024;
        unsigned w2 = (unsigned)(__float_as_uint(a0[g]) >> 16)
                    | ((__float_as_uint(a1[g]) >> 16) << 16);   // exact: bf16-valued
        *(unsigned*)(void*)(orow + 512 + tid * 2) = w2;
    }
    __syncthreads();
}

// ---------------- the persistent mega-kernel: 10 phases, 9 grid barriers ----------------
__global__ __launch_bounds__(256, 3) void k_mega(
    const float* __restrict__ z, const float* __restrict__ W1a, const float* __restrict__ b1a,
    const float* __restrict__ W1b, const float* __restrict__ b1b,
    const float* __restrict__ W1c, const float* __restrict__ b1c,
    const float* __restrict__ Wx1, const float* __restrict__ bx1,
    const float* __restrict__ W2a, const float* __restrict__ b2a,
    const float* __restrict__ W2b, const float* __restrict__ b2b,
    const float* __restrict__ W2c, const float* __restrict__ b2c,
    const float* __restrict__ Wx2, const float* __restrict__ bx2,
    unsigned short* __restrict__ WP, unsigned short* __restrict__ X1P,
    unsigned short* __restrict__ XMP, unsigned short* __restrict__ X2P,
    unsigned short* __restrict__ X3P, unsigned short* __restrict__ X4P,
    float* __restrict__ c1, unsigned* __restrict__ globE, float* __restrict__ gbias,
    float* __restrict__ hacc1, float* __restrict__ hacc2,
    float* __restrict__ zbase, unsigned* cnt,
    float* __restrict__ out0, float* __restrict__ out1, float* __restrict__ out2) {

    __shared__ __align__(16) char sm[32768];
    const int blk = blockIdx.x, tid = threadIdx.x;
    const int lane = tid & 63, wv = tid >> 6;

    unsigned short* WP1b = WP;
    unsigned short* WP1c = WP + 524288;
    unsigned short* WP2b = WP + 1048576;
    unsigned short* WP2c = WP + 1572864;
    unsigned short* WP2a = WP + 2097152;
    const int BIG = 1 << 30;
    const float* fine = out2;

    // ---- P0: pack weights (1,572,864 elems = 768 x 2048) + zero accs + c1 GEMV ----
    #pragma unroll 1
    for (int i = 0; i < 8; ++i) {
        int idx = blk * 2048 + i * 256 + tid;
        const float* src; unsigned short* dst; int o, k, K, in_ld; bool need_lo;
        if (idx < 1048576) {
            int which = idx >> 18; int local = idx & 262143;
            K = 512; in_ld = 512;
            src = (which == 0) ? W1b : (which == 1) ? W1c : (which == 2) ? W2b : W2c;
            dst = WP + (long)which * 524288;
            o = local >> 9; k = local & 511;
            need_lo = (which < 2);
        } else {
            int local = idx - 1048576;
            K = 1024; in_ld = 1536; src = W2a; dst = WP2a;
            o = local >> 10; k = local & 1023;
            need_lo = false;
        }
        float v = src[(long)o * in_ld + k];
        unsigned short hi = f2bf(v);
        dst[(long)o * 2 * K + k] = hi;
        if (need_lo) dst[(long)o * 2 * K + K + k] = f2bf(v - bf2f(hi));
    }
    if (blk < 256) {
        int gid = blk * 4 + wv;      // 0..1023
        int b = gid >> 9, o = gid & 511;
        float acc = 0.f;
        const float* wr = W1a + (long)o * 514;
        const float* zb = z + b * 512;
        for (int k = lane; k < 512; k += 64) acc += wr[k] * zb[k];
        #pragma unroll
        for (int off = 32; off > 0; off >>= 1) acc += __shfl_down(acc, off, 64);
        if (lane == 0) c1[gid] = acc + b1a[o];
    } else {
        int l = (blk - 256) * 256 + tid;
        if (l < ZERO_WORDS) zbase[l] = 0.f;
    }
    gridbar(cnt, NBLK * 1);

    // ---- P1: layer 1a (12288 virtual blocks -> 16 per real block) ----
    #pragma unroll 1
    for (int i = 0; i < 16; ++i) {
        int vbx = blk * 16 + i;
        int r = vbx >> 1;
        int o = ((vbx & 1) << 8) + tid;
        int b, n, side;
        if (r < 2048) { b = r >> 10; n = r & 1023; side = 32; }
        else          { int r2 = r - 2048; b = r2 >> 11; n = r2 & 2047; side = 46; }
        int row, col;
        if (side == 32) { row = n >> 5; col = n & 31; }
        else            { row = n / 46; col = n - row * 46; }
        double inv = 1.0 / (double)(side - 1);
        float lx = (row == side - 1) ? 1.0f : (float)(row * inv);
        float ly = (col == side - 1) ? 1.0f : (float)(col * inv);
        float h = c1[b * 512 + o] + W1a[(long)o * 514 + 512] * lx + W1a[(long)o * 514 + 513] * ly;
        h = (h > 0.f) ? h : SLOPE * h;
        unsigned short hi = f2bf(h);
        X1P[(long)r * 1024 + o] = hi;
        X1P[(long)r * 1024 + 512 + o] = f2bf(h - bf2f(hi));
    }
    gridbar(cnt, NBLK * 2);

    // ---- P2: gemm1b (768 tiles, 1:1) ----
    gemm_tile<3>(sm, tid, (blk % 96) * 64, (blk / 96) * 64,
                 WP1b, 1024, X1P, 1024, 512, b1b, BIG,
                 XMP, 1024, 512, 0, 0, nullptr, nullptr, nullptr, 0);
    gridbar(cnt, NBLK * 3);

    // ---- P3: gemm1c (+hacc1/globE epilogue) ----
    gemm_tile<3>(sm, tid, (blk % 96) * 64, (blk / 96) * 64,
                 WP1c, 1024, XMP, 1024, 512, b1c, BIG,
                 X2P, 1024, 0, 2048, 2048, Wx1, hacc1, globE, 2048);
    gridbar(cnt, NBLK * 4);

    // ---- P4: sigmoid heads (blocks 256+) + gbias GEMV (blocks 0-255) ----
    if (blk >= 256) {
        int r = (blk - 256) * 256 + tid;
        if (r < 6144) {
            float* dst = (r < 2048) ? (out0 + (long)r * 3) : (out2 + (long)(r - 2048) * 3);
            #pragma unroll
            for (int ch = 0; ch < 3; ++ch) {
                float a = hacc1[(long)r * 4 + ch] + bx1[ch];
                dst[ch] = 1.f / (1.f + expf(-a)) - 0.5f;
            }
        }
    } else {
        int gid = blk * 4 + wv;      // 0..1023
        int b = gid >> 9, o = gid & 511;
        float acc = 0.f;
        const float* wr = W2a + (long)o * 1536 + 1024;
        for (int k = lane; k < 512; k += 64) acc += wr[k] * fdec(globE[b * 512 + k]);
        #pragma unroll
        for (int off = 32; off > 0; off >>= 1) acc += __shfl_down(acc, off, 64);
        if (lane == 0) gbias[gid] = acc + b2a[o];
    }
    gridbar(cnt, NBLK * 5);

    // ---- P5: ball query (512 tasks on blocks 0-511) ----
    if (blk < 512) ball_task(sm, tid, (blk & 255) * QG, blk >> 8, fine, X2P);
    gridbar(cnt, NBLK * 6);

    // ---- P6: gemm2a (512 tiles on blocks 0-511) ----
    if (blk < 512)
        gemm_tile<1>(sm, tid, (blk % 64) * 64, (blk / 64) * 64,
                     WP2a, 2048, X2P, 1024, 1024, gbias, 2048,
                     X3P, 512, 0, 0, 0, nullptr, nullptr, nullptr, 0);
    gridbar(cnt, NBLK * 7);

    // ---- P7: gemm2b ----
    if (blk < 512)
        gemm_tile<1>(sm, tid, (blk % 64) * 64, (blk / 64) * 64,
                     WP2b, 1024, X3P, 512, 512, b2b, BIG,
                     X4P, 512, 0, 0, 0, nullptr, nullptr, nullptr, 0);
    gridbar(cnt, NBLK * 8);

    // ---- P8: gemm2c (+hacc2 epilogue) ----
    if (blk < 512)
        gemm_tile<1>(sm, tid, (blk % 64) * 64, (blk / 64) * 64,
                     WP2c, 1024, X4P, 512, 512, b2c, BIG,
                     nullptr, 0, 0, 0, 0, Wx2, hacc2, nullptr, 0);
    gridbar(cnt, NBLK * 9);

    // ---- P9: final2 ----
    {
        int r = blk * 256 + tid;
        if (r < 4096) {
            #pragma unroll
            for (int ch = 0; ch < 3; ++ch) {
                float a = hacc2[(long)r * 4 + ch] + bx2[ch];
                out1[(long)r * 3 + ch] = fine[(long)r * 3 + ch]
                                       + 0.1f * (1.f / (1.f + expf(-a)) - 0.5f);
            }
        }
    }
}

// ---------------- launch: memset(counter) + one persistent kernel ----------------
extern "C" void kernel_launch(void* const* d_in, const int* in_sizes, int n_in,
                              void* d_out, int out_size, void* d_ws, size_t ws_size,
                              hipStream_t stream) {
    const float* z   = (const float*)d_in[0];
    const float* W1a = (const float*)d_in[1];
    const float* b1a = (const float*)d_in[2];
    const float* W1b = (const float*)d_in[3];
    const float* b1b = (const float*)d_in[4];
    const float* W1c = (const float*)d_in[5];
    const float* b1c = (const float*)d_in[6];
    const float* Wx1 = (const float*)d_in[7];
    const float* bx1 = (const float*)d_in[8];
    const float* W2a = (const float*)d_in[9];
    const float* b2a = (const float*)d_in[10];
    const float* W2b = (const float*)d_in[11];
    const float* b2b = (const float*)d_in[12];
    const float* W2c = (const float*)d_in[13];
    const float* b2c = (const float*)d_in[14];
    const float* Wx2 = (const float*)d_in[15];
    const float* bx2 = (const float*)d_in[16];

    char* wsb = (char*)d_ws;
    unsigned short* WP   = (unsigned short*)(wsb + OFF_WP);
    unsigned short* X1P  = (unsigned short*)(wsb + OFF_X1P);
    unsigned short* XMP  = (unsigned short*)(wsb + OFF_XMP);
    unsigned short* X2P  = (unsigned short*)(wsb + OFF_X2P);
    unsigned short* X3P  = (unsigned short*)(wsb + OFF_X3P);
    unsigned short* X4P  = (unsigned short*)(wsb + OFF_X4P);
    float*    c1    = (float*)(wsb + OFF_C1);
    unsigned* globE = (unsigned*)(wsb + OFF_GLOBE);
    float*    gbias = (float*)(wsb + OFF_GBIAS);
    float*    hacc1 = (float*)(wsb + OFF_HACC1);
    float*    hacc2 = (float*)(wsb + OFF_HACC2);
    unsigned* cnt   = (unsigned*)(wsb + OFF_CNT);

    float* out0 = (float*)d_out;          // (2,1024,3)
    float* out1 = out0 + B * N1 * 3;      // (2,2048,3)
    float* out2 = out1 + B * N2 * 3;      // (2,2048,3) fine_points

    hipMemsetAsync(cnt, 0, 4, stream);    // zero the grid-barrier counter (capture-legal)

    k_mega<<<NBLK, 256, 0, stream>>>(
        z, W1a, b1a, W1b, b1b, W1c, b1c, Wx1, bx1,
        W2a, b2a, W2b, b2b, W2c, b2c, Wx2, bx2,
        WP, X1P, XMP, X2P, X3P, X4P,
        c1, globE, gbias, hacc1, hacc2,
        (float*)(wsb + OFF_GLOBE), cnt,
        out0, out1, out2);
}

// Round 7
// 717.276 us; speedup vs baseline: 1.7182x; 1.7182x over previous
//
#include <hip/hip_runtime.h>
#include <math.h>

#define B 2
#define N1 1024
#define N2 2048
#define SLOPE 0.2f
#define QG 8          // queries per ball task
#define NBLK 768      // 3 blocks/CU x 256 CU -- co-resident by construction

typedef short bf16x8 __attribute__((ext_vector_type(8)));
typedef float f32x4 __attribute__((ext_vector_type(4)));
typedef unsigned short u16x4 __attribute__((ext_vector_type(4)));
typedef unsigned short u16x8 __attribute__((ext_vector_type(8)));

__device__ __forceinline__ unsigned short f2bf(float x) {
    unsigned int u = __float_as_uint(x);
    unsigned int r = (u + 0x7fffu + ((u >> 16) & 1u)) >> 16;   // RNE
    return (unsigned short)r;
}
__device__ __forceinline__ float bf2f(unsigned short h) {
    return __uint_as_float(((unsigned int)h) << 16);
}
__device__ __forceinline__ unsigned fenc(float f) {
    unsigned u = __float_as_uint(f);
    return (u & 0x80000000u) ? ~u : (u | 0x80000000u);
}
__device__ __forceinline__ float fdec(unsigned u) {
    unsigned b = (u & 0x80000000u) ? (u & 0x7FFFFFFFu) : ~u;
    return __uint_as_float(b);
}

// ---- ws byte offsets ----
#define OFF_WP     0
#define OFF_X1P    6291456
#define OFF_XMP    18874368
#define OFF_X2P    31457280
#define OFF_X3P    39845888
#define OFF_X4P    44040192
#define OFF_C1     48234496
#define OFF_GLOBE  48238592
#define OFF_GBIAS  48242688
#define OFF_HACC1  48246784   // [6144][4] f32
#define OFF_HACC2  48345088   // [4096][4] f32
#define OFF_CNT    48410624   // grid-barrier counter (zeroed by hipMemsetAsync)
#define ZERO_WORDS 43008      // globE..hacc2 end

// ---- device-wide barrier v2: fences ONLY at the endpoints, RELAXED polls ----
// Round-6 lesson: an agent-scope ACQUIRE per poll emits buffer_inv (L1+L2, since
// per-XCD L2s are non-coherent) -> 768 spinners storm-invalidate every cache on the
// chip (~124us/barrier, all counters ~0). Correct shape: release fence once, add
// RELAXED, spin on RELAXED atomic loads (coherent visibility, no invalidates),
// ONE acquire fence after exit. Bailout cap: fail visibly, never hang.
__device__ __forceinline__ void gridbar(unsigned* cnt, unsigned target) {
    __syncthreads();
    if (threadIdx.x == 0) {
        __builtin_amdgcn_fence(__ATOMIC_RELEASE, "agent");   // publish this phase's writes
        __hip_atomic_fetch_add(cnt, 1u, __ATOMIC_RELAXED, __HIP_MEMORY_SCOPE_AGENT);
        long it = 0;
        while (__hip_atomic_load(cnt, __ATOMIC_RELAXED, __HIP_MEMORY_SCOPE_AGENT) < target) {
            __builtin_amdgcn_s_sleep(4);
            if (++it > 2000000L) break;    // fail visibly, never hang
        }
        __builtin_amdgcn_fence(__ATOMIC_ACQUIRE, "agent");   // drop stale L1/L2 once
    }
    __syncthreads();
}

// ---------------- GEMM tile: TERMS=3 split-bf16, TERMS=1 plain bf16 ----------------
template<int TERMS>
__device__ __forceinline__ void gemm_tile(
    char* sm, int t, int nb0, int ob0,
    const unsigned short* __restrict__ Wp, int ldw,
    const unsigned short* __restrict__ Xp, int ldx,
    int K,
    const float* __restrict__ bias, int bias_div,
    unsigned short* __restrict__ Xn, int ldxn, int lo_off, int row_off, int pack_min,
    const float* __restrict__ Wx, float* __restrict__ hacc,
    unsigned* __restrict__ globE, int glob_min) {

    constexpr int NBUF  = (TERMS == 3) ? 1 : 2;
    constexpr int BUFSZ = (TERMS == 3) ? 32768 : 16384;
    constexpr int XBASE = (TERMS == 3) ? 16384 : 8192;

    const unsigned short* gp[8];
    int lo_[8];
    #pragma unroll
    for (int p = 0; p < 8; ++p) {
        const int T = p >> 1;
        if (TERMS == 1 && (T == 1 || T == 3)) continue;
        int j2 = ((p & 1) << 8) + t;
        int r = j2 >> 3, cl = j2 & 7, cs = cl ^ (r & 7);
        gp[p] = (T < 2)
            ? (Wp + (long)(ob0 + r) * ldw + ((T == 1) ? K : 0) + cs * 8)
            : (Xp + (long)(nb0 + r) * ldx + ((T == 3) ? K : 0) + cs * 8);
        const int reg = (TERMS == 3) ? p : ((p < 2) ? p : p - 2);
        lo_[p] = reg * 4096 + t * 16;
    }

    const int lane = t & 63, w = t >> 6;
    const int wy = w >> 1, wx = w & 1;
    const int quad = lane >> 4, l15 = lane & 15;
    const int xm = l15 & 7;
    const int rowA = (wy * 32 + l15) * 128;
    const int rowB = (wx * 32 + l15) * 128;
    const int ca0 = (quad ^ xm) * 16;
    const int ca1 = ((quad + 4) ^ xm) * 16;

    f32x4 acc[2][2];
    #pragma unroll
    for (int i = 0; i < 2; ++i)
        #pragma unroll
        for (int j = 0; j < 2; ++j) { f32x4 zz = {0.f, 0.f, 0.f, 0.f}; acc[i][j] = zz; }

    auto stage = [&](int buf, int k0) {
        #pragma unroll
        for (int p = 0; p < 8; ++p) {
            const int T = p >> 1;
            if (TERMS == 1 && (T == 1 || T == 3)) continue;
            __builtin_amdgcn_global_load_lds(
                (const __attribute__((address_space(1))) void*)(const void*)(gp[p] + k0),
                (__attribute__((address_space(3))) void*)(void*)(sm + buf * BUFSZ + lo_[p]),
                16, 0, 0);
        }
    };

    auto compute = [&](int buf) {
        char* smb = sm + buf * BUFSZ;
        #pragma unroll
        for (int sub = 0; sub < 2; ++sub) {
            const int cb = (sub == 0) ? ca0 : ca1;
            bf16x8 ah[2], bh[2];
            #pragma unroll
            for (int i = 0; i < 2; ++i)
                ah[i] = *(const bf16x8*)(const void*)(smb + rowA + i * 2048 + cb);
            #pragma unroll
            for (int j = 0; j < 2; ++j)
                bh[j] = *(const bf16x8*)(const void*)(smb + XBASE + rowB + j * 2048 + cb);
            if (TERMS == 3) {
                bf16x8 al[2], bl[2];
                #pragma unroll
                for (int i = 0; i < 2; ++i)
                    al[i] = *(const bf16x8*)(const void*)(smb + 8192 + rowA + i * 2048 + cb);
                #pragma unroll
                for (int j = 0; j < 2; ++j)
                    bl[j] = *(const bf16x8*)(const void*)(smb + 24576 + rowB + j * 2048 + cb);
                #pragma unroll
                for (int i = 0; i < 2; ++i)
                    #pragma unroll
                    for (int j = 0; j < 2; ++j) {
                        acc[i][j] = __builtin_amdgcn_mfma_f32_16x16x32_bf16(ah[i], bh[j], acc[i][j], 0, 0, 0);
                        acc[i][j] = __builtin_amdgcn_mfma_f32_16x16x32_bf16(ah[i], bl[j], acc[i][j], 0, 0, 0);
                        acc[i][j] = __builtin_amdgcn_mfma_f32_16x16x32_bf16(al[i], bh[j], acc[i][j], 0, 0, 0);
                    }
            } else {
                #pragma unroll
                for (int i = 0; i < 2; ++i)
                    #pragma unroll
                    for (int j = 0; j < 2; ++j)
                        acc[i][j] = __builtin_amdgcn_mfma_f32_16x16x32_bf16(ah[i], bh[j], acc[i][j], 0, 0, 0);
            }
        }
    };

    if constexpr (TERMS == 3) {
        for (int k0 = 0; k0 < K; k0 += 64) {
            stage(0, k0);
            __syncthreads();
            compute(0);
            __syncthreads();
        }
    } else {
        stage(0, 0);
        __syncthreads();
        int cur = 0;
        for (int k0 = 64; k0 < K; k0 += 64) {
            stage(cur ^ 1, k0);
            compute(cur);
            __syncthreads();
            cur ^= 1;
        }
        compute(cur);
    }

    // ---- epilogue ----
    float val[2][2][4];
    #pragma unroll
    for (int j = 0; j < 2; ++j) {
        int n = nb0 + wx * 32 + j * 16 + l15;
        int bidx0 = (bias_div >= (1 << 29)) ? 0 : (n / bias_div) * 512;
        #pragma unroll
        for (int i = 0; i < 2; ++i) {
            int ob = ob0 + wy * 32 + i * 16 + quad * 4;
            #pragma unroll
            for (int r = 0; r < 4; ++r) {
                float x = acc[i][j][r] + bias[bidx0 + ob + r];
                val[i][j][r] = (x > 0.f) ? x : SLOPE * x;
            }
        }
        if (Xn && n >= pack_min) {
            long nl = n - row_off;
            #pragma unroll
            for (int i = 0; i < 2; ++i) {
                int ob = ob0 + wy * 32 + i * 16 + quad * 4;
                u16x4 h4;
                #pragma unroll
                for (int r = 0; r < 4; ++r) h4[r] = f2bf(val[i][j][r]);
                *(u16x4*)(void*)(Xn + nl * ldxn + ob) = h4;
                if (lo_off) {
                    u16x4 l4;
                    #pragma unroll
                    for (int r = 0; r < 4; ++r) l4[r] = f2bf(val[i][j][r] - bf2f(h4[r]));
                    *(u16x4*)(void*)(Xn + nl * ldxn + lo_off + ob) = l4;
                }
            }
        }
    }

    if (hacc) {
        __syncthreads();
        float* smh = (float*)sm;                     // [64][4]
        unsigned* smg = (unsigned*)(sm + 1024);      // [64]
        smh[t] = 0.f;
        if (t < 64) smg[t] = 0u;
        __syncthreads();
        float wxv[3][2][4];
        #pragma unroll
        for (int ch = 0; ch < 3; ++ch)
            #pragma unroll
            for (int i = 0; i < 2; ++i)
                #pragma unroll
                for (int r = 0; r < 4; ++r)
                    wxv[ch][i][r] = Wx[ch * 512 + ob0 + wy * 32 + i * 16 + quad * 4 + r];
        #pragma unroll
        for (int j = 0; j < 2; ++j) {
            int nl = wx * 32 + j * 16 + l15;
            float p0 = 0.f, p1 = 0.f, p2 = 0.f;
            #pragma unroll
            for (int i = 0; i < 2; ++i)
                #pragma unroll
                for (int r = 0; r < 4; ++r) {
                    float v = val[i][j][r];
                    p0 += v * wxv[0][i][r];
                    p1 += v * wxv[1][i][r];
                    p2 += v * wxv[2][i][r];
                }
            atomicAdd(&smh[nl * 4 + 0], p0);
            atomicAdd(&smh[nl * 4 + 1], p1);
            atomicAdd(&smh[nl * 4 + 2], p2);
        }
        if (globE && nb0 >= glob_min) {
            #pragma unroll
            for (int i = 0; i < 2; ++i)
                #pragma unroll
                for (int r = 0; r < 4; ++r) {
                    float mx = fmaxf(val[i][0][r], val[i][1][r]);
                    atomicMax(&smg[wy * 32 + i * 16 + quad * 4 + r], fenc(mx));
                }
        }
        __syncthreads();
        if (t < 64) {
            atomicAdd(&hacc[(long)(nb0 + t) * 4 + 0], smh[t * 4 + 0]);
            atomicAdd(&hacc[(long)(nb0 + t) * 4 + 1], smh[t * 4 + 1]);
            atomicAdd(&hacc[(long)(nb0 + t) * 4 + 2], smh[t * 4 + 2]);
            if (globE && nb0 >= glob_min) {
                int b = (nb0 - glob_min) >> 11;
                atomicMax(&globE[b * 512 + ob0 + t], smg[t]);
            }
        }
        __syncthreads();
    }
}

// ---------------- ball task (8 queries): shared scan + union gather-max ----------------
struct BallSm {
    float pts[N2 * 3];          // 24576 B
    unsigned char mark[N2];     // 2048 B
    int wcnt[4][QG];            // 128 B
    int ulist[512];             // 2048 B
    int ucnt;
};
static_assert(sizeof(BallSm) <= 32768, "ball LDS overlay too big");

__device__ __forceinline__ void ball_task(char* smraw, int tid, int i0, int b,
                                          const float* __restrict__ fine,
                                          unsigned short* __restrict__ X2P) {
    BallSm* s = (BallSm*)smraw;
    int lane = tid & 63, wv = tid >> 6;

    const float* fb = fine + (long)b * N2 * 3;
    for (int l = tid; l < N2 * 3; l += 256) s->pts[l] = fb[l];
    *(int*)(void*)&s->mark[tid * 8] = 0;
    *(int*)(void*)&s->mark[tid * 8 + 4] = 0;
    if (tid == 0) s->ucnt = 0;
    __syncthreads();

    float cx[QG], cy[QG], cz[QG], sqc[QG];
    #pragma unroll
    for (int g = 0; g < QG; ++g) {
        cx[g] = s->pts[(i0 + g) * 3 + 0];
        cy[g] = s->pts[(i0 + g) * 3 + 1];
        cz[g] = s->pts[(i0 + g) * 3 + 2];
        sqc[g] = __fadd_rn(__fadd_rn(__fmul_rn(cx[g], cx[g]), __fmul_rn(cy[g], cy[g])),
                           __fmul_rn(cz[g], cz[g]));
    }

    int cnt[QG];
    #pragma unroll
    for (int g = 0; g < QG; ++g) cnt[g] = 0;

    for (int it = 0; it < N2 / 256; ++it) {
        int j = it * 256 + tid;
        float xj = s->pts[j * 3 + 0], yj = s->pts[j * 3 + 1], zj = s->pts[j * 3 + 2];
        float sqj = __fadd_rn(__fadd_rn(__fmul_rn(xj, xj), __fmul_rn(yj, yj)), __fmul_rn(zj, zj));
        unsigned long long bm[QG];
        #pragma unroll
        for (int g = 0; g < QG; ++g) {
            float dot = __fadd_rn(__fadd_rn(__fmul_rn(cx[g], xj), __fmul_rn(cy[g], yj)),
                                  __fmul_rn(cz[g], zj));
            float d2 = __fsub_rn(__fadd_rn(sqc[g], sqj), __fmul_rn(2.0f, dot));
            bm[g] = __ballot(d2 < 0.01f);
        }
        if (lane < QG) s->wcnt[wv][lane] = __popcll(bm[lane]);
        __syncthreads();
        unsigned mybits = 0;
        #pragma unroll
        for (int g = 0; g < QG; ++g) {
            int base = cnt[g];
            #pragma unroll
            for (int q = 0; q < 3; ++q) { if (q < wv) base += s->wcnt[q][g]; }
            int rank = base + __popcll(bm[g] & ((1ull << lane) - 1ull));
            if (((bm[g] >> lane) & 1ull) && rank < 64) mybits |= 1u << g;
            cnt[g] += s->wcnt[0][g] + s->wcnt[1][g] + s->wcnt[2][g] + s->wcnt[3][g];
        }
        s->mark[j] = (unsigned char)mybits;
        bool done = true;
        #pragma unroll
        for (int g = 0; g < QG; ++g) done = done && (cnt[g] >= 64);
        __syncthreads();
        if (done) break;                 // uniform
    }

    for (int it = 0; it < N2 / 256; ++it) {
        int j = it * 256 + tid;
        unsigned mk = s->mark[j];
        if (mk) { int r = atomicAdd(&s->ucnt, 1); s->ulist[r] = j | ((int)mk << 16); }
    }
    __syncthreads();
    int nu = __builtin_amdgcn_readfirstlane(s->ucnt);

    const unsigned short* hb = X2P + (long)b * N2 * 1024;
    float a0[QG], a1[QG];
    #pragma unroll
    for (int g = 0; g < QG; ++g) { a0[g] = -1e30f; a1[g] = -1e30f; }

    auto apply = [&](unsigned mk, unsigned v) {
        float f0 = bf2f((unsigned short)(v & 0xFFFFu));
        float f1 = bf2f((unsigned short)(v >> 16));
        #pragma unroll
        for (int g = 0; g < QG; ++g) {
            if (mk & (1u << g)) {
                a0[g] = fmaxf(a0[g], f0);
                a1[g] = fmaxf(a1[g], f1);
            }
        }
    };

    int u = 0;
    for (; u + 4 <= nu; u += 4) {
        int e0 = __builtin_amdgcn_readfirstlane(s->ulist[u + 0]);
        int e1 = __builtin_amdgcn_readfirstlane(s->ulist[u + 1]);
        int e2 = __builtin_amdgcn_readfirstlane(s->ulist[u + 2]);
        int e3 = __builtin_amdgcn_readfirstlane(s->ulist[u + 3]);
        unsigned v0 = *(const unsigned*)(const void*)(hb + (long)(e0 & 0xFFFF) * 1024 + tid * 2);
        unsigned v1 = *(const unsigned*)(const void*)(hb + (long)(e1 & 0xFFFF) * 1024 + tid * 2);
        unsigned v2 = *(const unsigned*)(const void*)(hb + (long)(e2 & 0xFFFF) * 1024 + tid * 2);
        unsigned v3 = *(const unsigned*)(const void*)(hb + (long)(e3 & 0xFFFF) * 1024 + tid * 2);
        apply(((unsigned)e0) >> 16, v0);
        apply(((unsigned)e1) >> 16, v1);
        apply(((unsigned)e2) >> 16, v2);
        apply(((unsigned)e3) >> 16, v3);
    }
    for (; u < nu; ++u) {
        int e = __builtin_amdgcn_readfirstlane(s->ulist[u]);
        unsigned v = *(const unsigned*)(const void*)(hb + (long)(e & 0xFFFF) * 1024 + tid * 2);
        apply(((unsigned)e) >> 16, v);
    }

    #pragma unroll
    for (int g = 0; g < QG; ++g) {
        unsigned short* orow = X2P + (long)(b * N2 + i0 + g) * 1024;
        unsigned w2 = (unsigned)(__float_as_uint(a0[g]) >> 16)
                    | ((__float_as_uint(a1[g]) >> 16) << 16);   // exact: bf16-valued
        *(unsigned*)(void*)(orow + 512 + tid * 2) = w2;
    }
    __syncthreads();
}

// ---------------- the persistent mega-kernel: 10 phases, 9 grid barriers ----------------
__global__ __launch_bounds__(256, 3) void k_mega(
    const float* __restrict__ z, const float* __restrict__ W1a, const float* __restrict__ b1a,
    const float* __restrict__ W1b, const float* __restrict__ b1b,
    const float* __restrict__ W1c, const float* __restrict__ b1c,
    const float* __restrict__ Wx1, const float* __restrict__ bx1,
    const float* __restrict__ W2a, const float* __restrict__ b2a,
    const float* __restrict__ W2b, const float* __restrict__ b2b,
    const float* __restrict__ W2c, const float* __restrict__ b2c,
    const float* __restrict__ Wx2, const float* __restrict__ bx2,
    unsigned short* __restrict__ WP, unsigned short* __restrict__ X1P,
    unsigned short* __restrict__ XMP, unsigned short* __restrict__ X2P,
    unsigned short* __restrict__ X3P, unsigned short* __restrict__ X4P,
    float* __restrict__ c1, unsigned* __restrict__ globE, float* __restrict__ gbias,
    float* __restrict__ hacc1, float* __restrict__ hacc2,
    float* __restrict__ zbase, unsigned* cnt,
    float* __restrict__ out0, float* __restrict__ out1, float* __restrict__ out2) {

    __shared__ __align__(16) char sm[32768];
    const int blk = blockIdx.x, tid = threadIdx.x;
    const int lane = tid & 63, wv = tid >> 6;

    unsigned short* WP1b = WP;
    unsigned short* WP1c = WP + 524288;
    unsigned short* WP2b = WP + 1048576;
    unsigned short* WP2c = WP + 1572864;
    unsigned short* WP2a = WP + 2097152;
    const int BIG = 1 << 30;
    const float* fine = out2;

    // ---- P0: pack weights (1,572,864 elems = 768 x 2048) + zero accs + c1 GEMV ----
    #pragma unroll 1
    for (int i = 0; i < 8; ++i) {
        int idx = blk * 2048 + i * 256 + tid;
        const float* src; unsigned short* dst; int o, k, K, in_ld; bool need_lo;
        if (idx < 1048576) {
            int which = idx >> 18; int local = idx & 262143;
            K = 512; in_ld = 512;
            src = (which == 0) ? W1b : (which == 1) ? W1c : (which == 2) ? W2b : W2c;
            dst = WP + (long)which * 524288;
            o = local >> 9; k = local & 511;
            need_lo = (which < 2);
        } else {
            int local = idx - 1048576;
            K = 1024; in_ld = 1536; src = W2a; dst = WP2a;
            o = local >> 10; k = local & 1023;
            need_lo = false;
        }
        float v = src[(long)o * in_ld + k];
        unsigned short hi = f2bf(v);
        dst[(long)o * 2 * K + k] = hi;
        if (need_lo) dst[(long)o * 2 * K + K + k] = f2bf(v - bf2f(hi));
    }
    if (blk < 256) {
        int gid = blk * 4 + wv;      // 0..1023
        int b = gid >> 9, o = gid & 511;
        float acc = 0.f;
        const float* wr = W1a + (long)o * 514;
        const float* zb = z + b * 512;
        for (int k = lane; k < 512; k += 64) acc += wr[k] * zb[k];
        #pragma unroll
        for (int off = 32; off > 0; off >>= 1) acc += __shfl_down(acc, off, 64);
        if (lane == 0) c1[gid] = acc + b1a[o];
    } else {
        int l = (blk - 256) * 256 + tid;
        if (l < ZERO_WORDS) zbase[l] = 0.f;
    }
    gridbar(cnt, NBLK * 1);

    // ---- P1: layer 1a (12288 virtual blocks -> 16 per real block) ----
    #pragma unroll 1
    for (int i = 0; i < 16; ++i) {
        int vbx = blk * 16 + i;
        int r = vbx >> 1;
        int o = ((vbx & 1) << 8) + tid;
        int b, n, side;
        if (r < 2048) { b = r >> 10; n = r & 1023; side = 32; }
        else          { int r2 = r - 2048; b = r2 >> 11; n = r2 & 2047; side = 46; }
        int row, col;
        if (side == 32) { row = n >> 5; col = n & 31; }
        else            { row = n / 46; col = n - row * 46; }
        double inv = 1.0 / (double)(side - 1);
        float lx = (row == side - 1) ? 1.0f : (float)(row * inv);
        float ly = (col == side - 1) ? 1.0f : (float)(col * inv);
        float h = c1[b * 512 + o] + W1a[(long)o * 514 + 512] * lx + W1a[(long)o * 514 + 513] * ly;
        h = (h > 0.f) ? h : SLOPE * h;
        unsigned short hi = f2bf(h);
        X1P[(long)r * 1024 + o] = hi;
        X1P[(long)r * 1024 + 512 + o] = f2bf(h - bf2f(hi));
    }
    gridbar(cnt, NBLK * 2);

    // ---- P2: gemm1b (768 tiles, 1:1) ----
    gemm_tile<3>(sm, tid, (blk % 96) * 64, (blk / 96) * 64,
                 WP1b, 1024, X1P, 1024, 512, b1b, BIG,
                 XMP, 1024, 512, 0, 0, nullptr, nullptr, nullptr, 0);
    gridbar(cnt, NBLK * 3);

    // ---- P3: gemm1c (+hacc1/globE epilogue) ----
    gemm_tile<3>(sm, tid, (blk % 96) * 64, (blk / 96) * 64,
                 WP1c, 1024, XMP, 1024, 512, b1c, BIG,
                 X2P, 1024, 0, 2048, 2048, Wx1, hacc1, globE, 2048);
    gridbar(cnt, NBLK * 4);

    // ---- P4: sigmoid heads (blocks 256+) + gbias GEMV (blocks 0-255) ----
    if (blk >= 256) {
        int r = (blk - 256) * 256 + tid;
        if (r < 6144) {
            float* dst = (r < 2048) ? (out0 + (long)r * 3) : (out2 + (long)(r - 2048) * 3);
            #pragma unroll
            for (int ch = 0; ch < 3; ++ch) {
                float a = hacc1[(long)r * 4 + ch] + bx1[ch];
                dst[ch] = 1.f / (1.f + expf(-a)) - 0.5f;
            }
        }
    } else {
        int gid = blk * 4 + wv;      // 0..1023
        int b = gid >> 9, o = gid & 511;
        float acc = 0.f;
        const float* wr = W2a + (long)o * 1536 + 1024;
        for (int k = lane; k < 512; k += 64) acc += wr[k] * fdec(globE[b * 512 + k]);
        #pragma unroll
        for (int off = 32; off > 0; off >>= 1) acc += __shfl_down(acc, off, 64);
        if (lane == 0) gbias[gid] = acc + b2a[o];
    }
    gridbar(cnt, NBLK * 5);

    // ---- P5: ball query (512 tasks on blocks 0-511) ----
    if (blk < 512) ball_task(sm, tid, (blk & 255) * QG, blk >> 8, fine, X2P);
    gridbar(cnt, NBLK * 6);

    // ---- P6: gemm2a (512 tiles on blocks 0-511) ----
    if (blk < 512)
        gemm_tile<1>(sm, tid, (blk % 64) * 64, (blk / 64) * 64,
                     WP2a, 2048, X2P, 1024, 1024, gbias, 2048,
                     X3P, 512, 0, 0, 0, nullptr, nullptr, nullptr, 0);
    gridbar(cnt, NBLK * 7);

    // ---- P7: gemm2b ----
    if (blk < 512)
        gemm_tile<1>(sm, tid, (blk % 64) * 64, (blk / 64) * 64,
                     WP2b, 1024, X3P, 512, 512, b2b, BIG,
                     X4P, 512, 0, 0, 0, nullptr, nullptr, nullptr, 0);
    gridbar(cnt, NBLK * 8);

    // ---- P8: gemm2c (+hacc2 epilogue) ----
    if (blk < 512)
        gemm_tile<1>(sm, tid, (blk % 64) * 64, (blk / 64) * 64,
                     WP2c, 1024, X4P, 512, 512, b2c, BIG,
                     nullptr, 0, 0, 0, 0, Wx2, hacc2, nullptr, 0);
    gridbar(cnt, NBLK * 9);

    // ---- P9: final2 ----
    {
        int r = blk * 256 + tid;
        if (r < 4096) {
            #pragma unroll
            for (int ch = 0; ch < 3; ++ch) {
                float a = hacc2[(long)r * 4 + ch] + bx2[ch];
                out1[(long)r * 3 + ch] = fine[(long)r * 3 + ch]
                                       + 0.1f * (1.f / (1.f + expf(-a)) - 0.5f);
            }
        }
    }
}

// ---------------- launch: memset(counter) + one persistent kernel ----------------
extern "C" void kernel_launch(void* const* d_in, const int* in_sizes, int n_in,
                              void* d_out, int out_size, void* d_ws, size_t ws_size,
                              hipStream_t stream) {
    const float* z   = (const float*)d_in[0];
    const float* W1a = (const float*)d_in[1];
    const float* b1a = (const float*)d_in[2];
    const float* W1b = (const float*)d_in[3];
    const float* b1b = (const float*)d_in[4];
    const float* W1c = (const float*)d_in[5];
    const float* b1c = (const float*)d_in[6];
    const float* Wx1 = (const float*)d_in[7];
    const float* bx1 = (const float*)d_in[8];
    const float* W2a = (const float*)d_in[9];
    const float* b2a = (const float*)d_in[10];
    const float* W2b = (const float*)d_in[11];
    const float* b2b = (const float*)d_in[12];
    const float* W2c = (const float*)d_in[13];
    const float* b2c = (const float*)d_in[14];
    const float* Wx2 = (const float*)d_in[15];
    const float* bx2 = (const float*)d_in[16];

    char* wsb = (char*)d_ws;
    unsigned short* WP   = (unsigned short*)(wsb + OFF_WP);
    unsigned short* X1P  = (unsigned short*)(wsb + OFF_X1P);
    unsigned short* XMP  = (unsigned short*)(wsb + OFF_XMP);
    unsigned short* X2P  = (unsigned short*)(wsb + OFF_X2P);
    unsigned short* X3P  = (unsigned short*)(wsb + OFF_X3P);
    unsigned short* X4P  = (unsigned short*)(wsb + OFF_X4P);
    float*    c1    = (float*)(wsb + OFF_C1);
    unsigned* globE = (unsigned*)(wsb + OFF_GLOBE);
    float*    gbias = (float*)(wsb + OFF_GBIAS);
    float*    hacc1 = (float*)(wsb + OFF_HACC1);
    float*    hacc2 = (float*)(wsb + OFF_HACC2);
    unsigned* cnt   = (unsigned*)(wsb + OFF_CNT);

    float* out0 = (float*)d_out;          // (2,1024,3)
    float* out1 = out0 + B * N1 * 3;      // (2,2048,3)
    float* out2 = out1 + B * N2 * 3;      // (2,2048,3) fine_points

    hipMemsetAsync(cnt, 0, 4, stream);    // zero the grid-barrier counter (capture-legal)

    k_mega<<<NBLK, 256, 0, stream>>>(
        z, W1a, b1a, W1b, b1b, W1c, b1c, Wx1, bx1,
        W2a, b2a, W2b, b2b, W2c, b2c, Wx2, bx2,
        WP, X1P, XMP, X2P, X3P, X4P,
        c1, globE, gbias, hacc1, hacc2,
        (float*)(wsb + OFF_GLOBE), cnt,
        out0, out1, out2);
}

// Round 8
// 387.993 us; speedup vs baseline: 3.1764x; 1.8487x over previous
//
#include <hip/hip_runtime.h>
#include <math.h>

#define B 2
#define N1 1024
#define N2 2048
#define SLOPE 0.2f
#define QG 8          // queries per ball task
#define NBLK 768      // 3 blocks/CU x 256 CU -- co-resident by construction

typedef short bf16x8 __attribute__((ext_vector_type(8)));
typedef float f32x4 __attribute__((ext_vector_type(4)));
typedef unsigned short u16x4 __attribute__((ext_vector_type(4)));
typedef unsigned short u16x8 __attribute__((ext_vector_type(8)));

__device__ __forceinline__ unsigned short f2bf(float x) {
    unsigned int u = __float_as_uint(x);
    unsigned int r = (u + 0x7fffu + ((u >> 16) & 1u)) >> 16;   // RNE
    return (unsigned short)r;
}
__device__ __forceinline__ float bf2f(unsigned short h) {
    return __uint_as_float(((unsigned int)h) << 16);
}
__device__ __forceinline__ unsigned fenc(float f) {
    unsigned u = __float_as_uint(f);
    return (u & 0x80000000u) ? ~u : (u | 0x80000000u);
}
__device__ __forceinline__ float fdec(unsigned u) {
    unsigned b = (u & 0x80000000u) ? (u & 0x7FFFFFFFu) : ~u;
    return __uint_as_float(b);
}

// ---- ws byte offsets ----
#define OFF_WP     0
#define OFF_X1P    6291456
#define OFF_XMP    18874368
#define OFF_X2P    31457280
#define OFF_X3P    39845888
#define OFF_X4P    44040192
#define OFF_C1     48234496
#define OFF_GLOBE  48238592
#define OFF_GBIAS  48242688
#define OFF_HACC1  48246784   // [6144][4] f32
#define OFF_HACC2  48345088   // [4096][4] f32
#define OFF_CNT    48410624   // barrier area: 8 arrival + 8 release lines (4KB, memset)
#define ZERO_WORDS 43008      // globE..hacc2 end

// ---- device-wide barrier v3: two-level, replicated release, endpoint fences ----
// Round-7 lesson: 767 pollers on ONE line (even RELAXED) saturate its coherence
// point; the 768 arrival adds queue behind the poll flood (~60us/barrier).
// v3: 8 arrival counters on separate 256B lines (blk&7 -> 96 adds/line); ONE
// master polls them (single poller, no contention) and fans out to 8 replicated
// release words; waiters poll only their release word with ~0.43us backoff
// (<=95 pollers/line, value changes once). Fences only at endpoints (v2 shape).
__device__ __forceinline__ void gridbar(char* bar, unsigned phase, int blk) {
    __syncthreads();
    if (threadIdx.x == 0) {
        const int g = blk & 7;
        unsigned* arr = (unsigned*)(bar + g * 256);
        unsigned* rel = (unsigned*)(bar + 2048 + g * 256);
        __builtin_amdgcn_fence(__ATOMIC_RELEASE, "agent");   // publish this phase's writes
        __hip_atomic_fetch_add(arr, 1u, __ATOMIC_RELAXED, __HIP_MEMORY_SCOPE_AGENT);
        if (blk == 0) {
            long it = 0;
            for (int gg = 0; gg < 8; ) {
                unsigned* a = (unsigned*)(bar + gg * 256);
                if (__hip_atomic_load(a, __ATOMIC_RELAXED, __HIP_MEMORY_SCOPE_AGENT)
                        >= 96u * phase) { ++gg; continue; }
                __builtin_amdgcn_s_sleep(1);
                if (++it > 5000000L) break;    // fail visibly, never hang
            }
            #pragma unroll
            for (int gg = 0; gg < 8; ++gg) {
                unsigned* r = (unsigned*)(bar + 2048 + gg * 256);
                __hip_atomic_store(r, phase, __ATOMIC_RELAXED, __HIP_MEMORY_SCOPE_AGENT);
            }
        } else {
            long it = 0;
            while (__hip_atomic_load(rel, __ATOMIC_RELAXED, __HIP_MEMORY_SCOPE_AGENT) < phase) {
                __builtin_amdgcn_s_sleep(16);
                if (++it > 300000L) break;     // ~130ms cap: fail visibly, never hang
            }
        }
        __builtin_amdgcn_fence(__ATOMIC_ACQUIRE, "agent");   // drop stale L1/L2 once
    }
    __syncthreads();
}

// ---------------- GEMM tile: TERMS=3 split-bf16, TERMS=1 plain bf16 ----------------
template<int TERMS>
__device__ __forceinline__ void gemm_tile(
    char* sm, int t, int nb0, int ob0,
    const unsigned short* __restrict__ Wp, int ldw,
    const unsigned short* __restrict__ Xp, int ldx,
    int K,
    const float* __restrict__ bias, int bias_div,
    unsigned short* __restrict__ Xn, int ldxn, int lo_off, int row_off, int pack_min,
    const float* __restrict__ Wx, float* __restrict__ hacc,
    unsigned* __restrict__ globE, int glob_min) {

    constexpr int NBUF  = (TERMS == 3) ? 1 : 2;
    constexpr int BUFSZ = (TERMS == 3) ? 32768 : 16384;
    constexpr int XBASE = (TERMS == 3) ? 16384 : 8192;

    const unsigned short* gp[8];
    int lo_[8];
    #pragma unroll
    for (int p = 0; p < 8; ++p) {
        const int T = p >> 1;
        if (TERMS == 1 && (T == 1 || T == 3)) continue;
        int j2 = ((p & 1) << 8) + t;
        int r = j2 >> 3, cl = j2 & 7, cs = cl ^ (r & 7);
        gp[p] = (T < 2)
            ? (Wp + (long)(ob0 + r) * ldw + ((T == 1) ? K : 0) + cs * 8)
            : (Xp + (long)(nb0 + r) * ldx + ((T == 3) ? K : 0) + cs * 8);
        const int reg = (TERMS == 3) ? p : ((p < 2) ? p : p - 2);
        lo_[p] = reg * 4096 + t * 16;
    }

    const int lane = t & 63, w = t >> 6;
    const int wy = w >> 1, wx = w & 1;
    const int quad = lane >> 4, l15 = lane & 15;
    const int xm = l15 & 7;
    const int rowA = (wy * 32 + l15) * 128;
    const int rowB = (wx * 32 + l15) * 128;
    const int ca0 = (quad ^ xm) * 16;
    const int ca1 = ((quad + 4) ^ xm) * 16;

    f32x4 acc[2][2];
    #pragma unroll
    for (int i = 0; i < 2; ++i)
        #pragma unroll
        for (int j = 0; j < 2; ++j) { f32x4 zz = {0.f, 0.f, 0.f, 0.f}; acc[i][j] = zz; }

    auto stage = [&](int buf, int k0) {
        #pragma unroll
        for (int p = 0; p < 8; ++p) {
            const int T = p >> 1;
            if (TERMS == 1 && (T == 1 || T == 3)) continue;
            __builtin_amdgcn_global_load_lds(
                (const __attribute__((address_space(1))) void*)(const void*)(gp[p] + k0),
                (__attribute__((address_space(3))) void*)(void*)(sm + buf * BUFSZ + lo_[p]),
                16, 0, 0);
        }
    };

    auto compute = [&](int buf) {
        char* smb = sm + buf * BUFSZ;
        #pragma unroll
        for (int sub = 0; sub < 2; ++sub) {
            const int cb = (sub == 0) ? ca0 : ca1;
            bf16x8 ah[2], bh[2];
            #pragma unroll
            for (int i = 0; i < 2; ++i)
                ah[i] = *(const bf16x8*)(const void*)(smb + rowA + i * 2048 + cb);
            #pragma unroll
            for (int j = 0; j < 2; ++j)
                bh[j] = *(const bf16x8*)(const void*)(smb + XBASE + rowB + j * 2048 + cb);
            if (TERMS == 3) {
                bf16x8 al[2], bl[2];
                #pragma unroll
                for (int i = 0; i < 2; ++i)
                    al[i] = *(const bf16x8*)(const void*)(smb + 8192 + rowA + i * 2048 + cb);
                #pragma unroll
                for (int j = 0; j < 2; ++j)
                    bl[j] = *(const bf16x8*)(const void*)(smb + 24576 + rowB + j * 2048 + cb);
                #pragma unroll
                for (int i = 0; i < 2; ++i)
                    #pragma unroll
                    for (int j = 0; j < 2; ++j) {
                        acc[i][j] = __builtin_amdgcn_mfma_f32_16x16x32_bf16(ah[i], bh[j], acc[i][j], 0, 0, 0);
                        acc[i][j] = __builtin_amdgcn_mfma_f32_16x16x32_bf16(ah[i], bl[j], acc[i][j], 0, 0, 0);
                        acc[i][j] = __builtin_amdgcn_mfma_f32_16x16x32_bf16(al[i], bh[j], acc[i][j], 0, 0, 0);
                    }
            } else {
                #pragma unroll
                for (int i = 0; i < 2; ++i)
                    #pragma unroll
                    for (int j = 0; j < 2; ++j)
                        acc[i][j] = __builtin_amdgcn_mfma_f32_16x16x32_bf16(ah[i], bh[j], acc[i][j], 0, 0, 0);
            }
        }
    };

    if constexpr (TERMS == 3) {
        for (int k0 = 0; k0 < K; k0 += 64) {
            stage(0, k0);
            __syncthreads();
            compute(0);
            __syncthreads();
        }
    } else {
        stage(0, 0);
        __syncthreads();
        int cur = 0;
        for (int k0 = 64; k0 < K; k0 += 64) {
            stage(cur ^ 1, k0);
            compute(cur);
            __syncthreads();
            cur ^= 1;
        }
        compute(cur);
    }

    // ---- epilogue ----
    float val[2][2][4];
    #pragma unroll
    for (int j = 0; j < 2; ++j) {
        int n = nb0 + wx * 32 + j * 16 + l15;
        int bidx0 = (bias_div >= (1 << 29)) ? 0 : (n / bias_div) * 512;
        #pragma unroll
        for (int i = 0; i < 2; ++i) {
            int ob = ob0 + wy * 32 + i * 16 + quad * 4;
            #pragma unroll
            for (int r = 0; r < 4; ++r) {
                float x = acc[i][j][r] + bias[bidx0 + ob + r];
                val[i][j][r] = (x > 0.f) ? x : SLOPE * x;
            }
        }
        if (Xn && n >= pack_min) {
            long nl = n - row_off;
            #pragma unroll
            for (int i = 0; i < 2; ++i) {
                int ob = ob0 + wy * 32 + i * 16 + quad * 4;
                u16x4 h4;
                #pragma unroll
                for (int r = 0; r < 4; ++r) h4[r] = f2bf(val[i][j][r]);
                *(u16x4*)(void*)(Xn + nl * ldxn + ob) = h4;
                if (lo_off) {
                    u16x4 l4;
                    #pragma unroll
                    for (int r = 0; r < 4; ++r) l4[r] = f2bf(val[i][j][r] - bf2f(h4[r]));
                    *(u16x4*)(void*)(Xn + nl * ldxn + lo_off + ob) = l4;
                }
            }
        }
    }

    if (hacc) {
        __syncthreads();
        float* smh = (float*)sm;                     // [64][4]
        unsigned* smg = (unsigned*)(sm + 1024);      // [64]
        smh[t] = 0.f;
        if (t < 64) smg[t] = 0u;
        __syncthreads();
        float wxv[3][2][4];
        #pragma unroll
        for (int ch = 0; ch < 3; ++ch)
            #pragma unroll
            for (int i = 0; i < 2; ++i)
                #pragma unroll
                for (int r = 0; r < 4; ++r)
                    wxv[ch][i][r] = Wx[ch * 512 + ob0 + wy * 32 + i * 16 + quad * 4 + r];
        #pragma unroll
        for (int j = 0; j < 2; ++j) {
            int nl = wx * 32 + j * 16 + l15;
            float p0 = 0.f, p1 = 0.f, p2 = 0.f;
            #pragma unroll
            for (int i = 0; i < 2; ++i)
                #pragma unroll
                for (int r = 0; r < 4; ++r) {
                    float v = val[i][j][r];
                    p0 += v * wxv[0][i][r];
                    p1 += v * wxv[1][i][r];
                    p2 += v * wxv[2][i][r];
                }
            atomicAdd(&smh[nl * 4 + 0], p0);
            atomicAdd(&smh[nl * 4 + 1], p1);
            atomicAdd(&smh[nl * 4 + 2], p2);
        }
        if (globE && nb0 >= glob_min) {
            #pragma unroll
            for (int i = 0; i < 2; ++i)
                #pragma unroll
                for (int r = 0; r < 4; ++r) {
                    float mx = fmaxf(val[i][0][r], val[i][1][r]);
                    atomicMax(&smg[wy * 32 + i * 16 + quad * 4 + r], fenc(mx));
                }
        }
        __syncthreads();
        if (t < 64) {
            atomicAdd(&hacc[(long)(nb0 + t) * 4 + 0], smh[t * 4 + 0]);
            atomicAdd(&hacc[(long)(nb0 + t) * 4 + 1], smh[t * 4 + 1]);
            atomicAdd(&hacc[(long)(nb0 + t) * 4 + 2], smh[t * 4 + 2]);
            if (globE && nb0 >= glob_min) {
                int b = (nb0 - glob_min) >> 11;
                atomicMax(&globE[b * 512 + ob0 + t], smg[t]);
            }
        }
        __syncthreads();
    }
}

// ---------------- ball task (8 queries): shared scan + union gather-max ----------------
struct BallSm {
    float pts[N2 * 3];          // 24576 B
    unsigned char mark[N2];     // 2048 B
    int wcnt[4][QG];            // 128 B
    int ulist[512];             // 2048 B
    int ucnt;
};
static_assert(sizeof(BallSm) <= 32768, "ball LDS overlay too big");

__device__ __forceinline__ void ball_task(char* smraw, int tid, int i0, int b,
                                          const float* __restrict__ fine,
                                          unsigned short* __restrict__ X2P) {
    BallSm* s = (BallSm*)smraw;
    int lane = tid & 63, wv = tid >> 6;

    const float* fb = fine + (long)b * N2 * 3;
    for (int l = tid; l < N2 * 3; l += 256) s->pts[l] = fb[l];
    *(int*)(void*)&s->mark[tid * 8] = 0;
    *(int*)(void*)&s->mark[tid * 8 + 4] = 0;
    if (tid == 0) s->ucnt = 0;
    __syncthreads();

    float cx[QG], cy[QG], cz[QG], sqc[QG];
    #pragma unroll
    for (int g = 0; g < QG; ++g) {
        cx[g] = s->pts[(i0 + g) * 3 + 0];
        cy[g] = s->pts[(i0 + g) * 3 + 1];
        cz[g] = s->pts[(i0 + g) * 3 + 2];
        sqc[g] = __fadd_rn(__fadd_rn(__fmul_rn(cx[g], cx[g]), __fmul_rn(cy[g], cy[g])),
                           __fmul_rn(cz[g], cz[g]));
    }

    int cnt[QG];
    #pragma unroll
    for (int g = 0; g < QG; ++g) cnt[g] = 0;

    for (int it = 0; it < N2 / 256; ++it) {
        int j = it * 256 + tid;
        float xj = s->pts[j * 3 + 0], yj = s->pts[j * 3 + 1], zj = s->pts[j * 3 + 2];
        float sqj = __fadd_rn(__fadd_rn(__fmul_rn(xj, xj), __fmul_rn(yj, yj)), __fmul_rn(zj, zj));
        unsigned long long bm[QG];
        #pragma unroll
        for (int g = 0; g < QG; ++g) {
            float dot = __fadd_rn(__fadd_rn(__fmul_rn(cx[g], xj), __fmul_rn(cy[g], yj)),
                                  __fmul_rn(cz[g], zj));
            float d2 = __fsub_rn(__fadd_rn(sqc[g], sqj), __fmul_rn(2.0f, dot));
            bm[g] = __ballot(d2 < 0.01f);
        }
        if (lane < QG) s->wcnt[wv][lane] = __popcll(bm[lane]);
        __syncthreads();
        unsigned mybits = 0;
        #pragma unroll
        for (int g = 0; g < QG; ++g) {
            int base = cnt[g];
            #pragma unroll
            for (int q = 0; q < 3; ++q) { if (q < wv) base += s->wcnt[q][g]; }
            int rank = base + __popcll(bm[g] & ((1ull << lane) - 1ull));
            if (((bm[g] >> lane) & 1ull) && rank < 64) mybits |= 1u << g;
            cnt[g] += s->wcnt[0][g] + s->wcnt[1][g] + s->wcnt[2][g] + s->wcnt[3][g];
        }
        s->mark[j] = (unsigned char)mybits;
        bool done = true;
        #pragma unroll
        for (int g = 0; g < QG; ++g) done = done && (cnt[g] >= 64);
        __syncthreads();
        if (done) break;                 // uniform
    }

    for (int it = 0; it < N2 / 256; ++it) {
        int j = it * 256 + tid;
        unsigned mk = s->mark[j];
        if (mk) { int r = atomicAdd(&s->ucnt, 1); s->ulist[r] = j | ((int)mk << 16); }
    }
    __syncthreads();
    int nu = __builtin_amdgcn_readfirstlane(s->ucnt);

    const unsigned short* hb = X2P + (long)b * N2 * 1024;
    float a0[QG], a1[QG];
    #pragma unroll
    for (int g = 0; g < QG; ++g) { a0[g] = -1e30f; a1[g] = -1e30f; }

    auto apply = [&](unsigned mk, unsigned v) {
        float f0 = bf2f((unsigned short)(v & 0xFFFFu));
        float f1 = bf2f((unsigned short)(v >> 16));
        #pragma unroll
        for (int g = 0; g < QG; ++g) {
            if (mk & (1u << g)) {
                a0[g] = fmaxf(a0[g], f0);
                a1[g] = fmaxf(a1[g], f1);
            }
        }
    };

    int u = 0;
    for (; u + 4 <= nu; u += 4) {
        int e0 = __builtin_amdgcn_readfirstlane(s->ulist[u + 0]);
        int e1 = __builtin_amdgcn_readfirstlane(s->ulist[u + 1]);
        int e2 = __builtin_amdgcn_readfirstlane(s->ulist[u + 2]);
        int e3 = __builtin_amdgcn_readfirstlane(s->ulist[u + 3]);
        unsigned v0 = *(const unsigned*)(const void*)(hb + (long)(e0 & 0xFFFF) * 1024 + tid * 2);
        unsigned v1 = *(const unsigned*)(const void*)(hb + (long)(e1 & 0xFFFF) * 1024 + tid * 2);
        unsigned v2 = *(const unsigned*)(const void*)(hb + (long)(e2 & 0xFFFF) * 1024 + tid * 2);
        unsigned v3 = *(const unsigned*)(const void*)(hb + (long)(e3 & 0xFFFF) * 1024 + tid * 2);
        apply(((unsigned)e0) >> 16, v0);
        apply(((unsigned)e1) >> 16, v1);
        apply(((unsigned)e2) >> 16, v2);
        apply(((unsigned)e3) >> 16, v3);
    }
    for (; u < nu; ++u) {
        int e = __builtin_amdgcn_readfirstlane(s->ulist[u]);
        unsigned v = *(const unsigned*)(const void*)(hb + (long)(e & 0xFFFF) * 1024 + tid * 2);
        apply(((unsigned)e) >> 16, v);
    }

    #pragma unroll
    for (int g = 0; g < QG; ++g) {
        unsigned short* orow = X2P + (long)(b * N2 + i0 + g) * 1024;
        unsigned w2 = (unsigned)(__float_as_uint(a0[g]) >> 16)
                    | ((__float_as_uint(a1[g]) >> 16) << 16);   // exact: bf16-valued
        *(unsigned*)(void*)(orow + 512 + tid * 2) = w2;
    }
    __syncthreads();
}

// ---------------- the persistent mega-kernel: 10 phases, 9 grid barriers ----------------
__global__ __launch_bounds__(256, 3) void k_mega(
    const float* __restrict__ z, const float* __restrict__ W1a, const float* __restrict__ b1a,
    const float* __restrict__ W1b, const float* __restrict__ b1b,
    const float* __restrict__ W1c, const float* __restrict__ b1c,
    const float* __restrict__ Wx1, const float* __restrict__ bx1,
    const float* __restrict__ W2a, const float* __restrict__ b2a,
    const float* __restrict__ W2b, const float* __restrict__ b2b,
    const float* __restrict__ W2c, const float* __restrict__ b2c,
    const float* __restrict__ Wx2, const float* __restrict__ bx2,
    unsigned short* __restrict__ WP, unsigned short* __restrict__ X1P,
    unsigned short* __restrict__ XMP, unsigned short* __restrict__ X2P,
    unsigned short* __restrict__ X3P, unsigned short* __restrict__ X4P,
    float* __restrict__ c1, unsigned* __restrict__ globE, float* __restrict__ gbias,
    float* __restrict__ hacc1, float* __restrict__ hacc2,
    float* __restrict__ zbase, char* bar,
    float* __restrict__ out0, float* __restrict__ out1, float* __restrict__ out2) {

    __shared__ __align__(16) char sm[32768];
    const int blk = blockIdx.x, tid = threadIdx.x;
    const int lane = tid & 63, wv = tid >> 6;

    unsigned short* WP1b = WP;
    unsigned short* WP1c = WP + 524288;
    unsigned short* WP2b = WP + 1048576;
    unsigned short* WP2c = WP + 1572864;
    unsigned short* WP2a = WP + 2097152;
    const int BIG = 1 << 30;
    const float* fine = out2;

    // ---- P0: pack weights (1,572,864 elems = 768 x 2048) + zero accs + c1 GEMV ----
    #pragma unroll 1
    for (int i = 0; i < 8; ++i) {
        int idx = blk * 2048 + i * 256 + tid;
        const float* src; unsigned short* dst; int o, k, K, in_ld; bool need_lo;
        if (idx < 1048576) {
            int which = idx >> 18; int local = idx & 262143;
            K = 512; in_ld = 512;
            src = (which == 0) ? W1b : (which == 1) ? W1c : (which == 2) ? W2b : W2c;
            dst = WP + (long)which * 524288;
            o = local >> 9; k = local & 511;
            need_lo = (which < 2);
        } else {
            int local = idx - 1048576;
            K = 1024; in_ld = 1536; src = W2a; dst = WP2a;
            o = local >> 10; k = local & 1023;
            need_lo = false;
        }
        float v = src[(long)o * in_ld + k];
        unsigned short hi = f2bf(v);
        dst[(long)o * 2 * K + k] = hi;
        if (need_lo) dst[(long)o * 2 * K + K + k] = f2bf(v - bf2f(hi));
    }
    if (blk < 256) {
        int gid = blk * 4 + wv;      // 0..1023
        int b = gid >> 9, o = gid & 511;
        float acc = 0.f;
        const float* wr = W1a + (long)o * 514;
        const float* zb = z + b * 512;
        for (int k = lane; k < 512; k += 64) acc += wr[k] * zb[k];
        #pragma unroll
        for (int off = 32; off > 0; off >>= 1) acc += __shfl_down(acc, off, 64);
        if (lane == 0) c1[gid] = acc + b1a[o];
    } else {
        int l = (blk - 256) * 256 + tid;
        if (l < ZERO_WORDS) zbase[l] = 0.f;
    }
    gridbar(bar, 1, blk);

    // ---- P1: layer 1a (12288 virtual blocks -> 16 per real block) ----
    #pragma unroll 1
    for (int i = 0; i < 16; ++i) {
        int vbx = blk * 16 + i;
        int r = vbx >> 1;
        int o = ((vbx & 1) << 8) + tid;
        int b, n, side;
        if (r < 2048) { b = r >> 10; n = r & 1023; side = 32; }
        else          { int r2 = r - 2048; b = r2 >> 11; n = r2 & 2047; side = 46; }
        int row, col;
        if (side == 32) { row = n >> 5; col = n & 31; }
        else            { row = n / 46; col = n - row * 46; }
        double inv = 1.0 / (double)(side - 1);
        float lx = (row == side - 1) ? 1.0f : (float)(row * inv);
        float ly = (col == side - 1) ? 1.0f : (float)(col * inv);
        float h = c1[b * 512 + o] + W1a[(long)o * 514 + 512] * lx + W1a[(long)o * 514 + 513] * ly;
        h = (h > 0.f) ? h : SLOPE * h;
        unsigned short hi = f2bf(h);
        X1P[(long)r * 1024 + o] = hi;
        X1P[(long)r * 1024 + 512 + o] = f2bf(h - bf2f(hi));
    }
    gridbar(bar, 2, blk);

    // ---- P2: gemm1b (768 tiles, 1:1) ----
    gemm_tile<3>(sm, tid, (blk % 96) * 64, (blk / 96) * 64,
                 WP1b, 1024, X1P, 1024, 512, b1b, BIG,
                 XMP, 1024, 512, 0, 0, nullptr, nullptr, nullptr, 0);
    gridbar(bar, 3, blk);

    // ---- P3: gemm1c (+hacc1/globE epilogue) ----
    gemm_tile<3>(sm, tid, (blk % 96) * 64, (blk / 96) * 64,
                 WP1c, 1024, XMP, 1024, 512, b1c, BIG,
                 X2P, 1024, 0, 2048, 2048, Wx1, hacc1, globE, 2048);
    gridbar(bar, 4, blk);

    // ---- P4: sigmoid heads (blocks 256+) + gbias GEMV (blocks 0-255) ----
    if (blk >= 256) {
        int r = (blk - 256) * 256 + tid;
        if (r < 6144) {
            float* dst = (r < 2048) ? (out0 + (long)r * 3) : (out2 + (long)(r - 2048) * 3);
            #pragma unroll
            for (int ch = 0; ch < 3; ++ch) {
                float a = hacc1[(long)r * 4 + ch] + bx1[ch];
                dst[ch] = 1.f / (1.f + expf(-a)) - 0.5f;
            }
        }
    } else {
        int gid = blk * 4 + wv;      // 0..1023
        int b = gid >> 9, o = gid & 511;
        float acc = 0.f;
        const float* wr = W2a + (long)o * 1536 + 1024;
        for (int k = lane; k < 512; k += 64) acc += wr[k] * fdec(globE[b * 512 + k]);
        #pragma unroll
        for (int off = 32; off > 0; off >>= 1) acc += __shfl_down(acc, off, 64);
        if (lane == 0) gbias[gid] = acc + b2a[o];
    }
    gridbar(bar, 5, blk);

    // ---- P5: ball query (512 tasks on blocks 0-511) ----
    if (blk < 512) ball_task(sm, tid, (blk & 255) * QG, blk >> 8, fine, X2P);
    gridbar(bar, 6, blk);

    // ---- P6: gemm2a (512 tiles on blocks 0-511) ----
    if (blk < 512)
        gemm_tile<1>(sm, tid, (blk % 64) * 64, (blk / 64) * 64,
                     WP2a, 2048, X2P, 1024, 1024, gbias, 2048,
                     X3P, 512, 0, 0, 0, nullptr, nullptr, nullptr, 0);
    gridbar(bar, 7, blk);

    // ---- P7: gemm2b ----
    if (blk < 512)
        gemm_tile<1>(sm, tid, (blk % 64) * 64, (blk / 64) * 64,
                     WP2b, 1024, X3P, 512, 512, b2b, BIG,
                     X4P, 512, 0, 0, 0, nullptr, nullptr, nullptr, 0);
    gridbar(bar, 8, blk);

    // ---- P8: gemm2c (+hacc2 epilogue) ----
    if (blk < 512)
        gemm_tile<1>(sm, tid, (blk % 64) * 64, (blk / 64) * 64,
                     WP2c, 1024, X4P, 512, 512, b2c, BIG,
                     nullptr, 0, 0, 0, 0, Wx2, hacc2, nullptr, 0);
    gridbar(bar, 9, blk);

    // ---- P9: final2 ----
    {
        int r = blk * 256 + tid;
        if (r < 4096) {
            #pragma unroll
            for (int ch = 0; ch < 3; ++ch) {
                float a = hacc2[(long)r * 4 + ch] + bx2[ch];
                out1[(long)r * 3 + ch] = fine[(long)r * 3 + ch]
                                       + 0.1f * (1.f / (1.f + expf(-a)) - 0.5f);
            }
        }
    }
}

// ---------------- launch: memset(barrier area) + one persistent kernel ----------------
extern "C" void kernel_launch(void* const* d_in, const int* in_sizes, int n_in,
                              void* d_out, int out_size, void* d_ws, size_t ws_size,
                              hipStream_t stream) {
    const float* z   = (const float*)d_in[0];
    const float* W1a = (const float*)d_in[1];
    const float* b1a = (const float*)d_in[2];
    const float* W1b = (const float*)d_in[3];
    const float* b1b = (const float*)d_in[4];
    const float* W1c = (const float*)d_in[5];
    const float* b1c = (const float*)d_in[6];
    const float* Wx1 = (const float*)d_in[7];
    const float* bx1 = (const float*)d_in[8];
    const float* W2a = (const float*)d_in[9];
    const float* b2a = (const float*)d_in[10];
    const float* W2b = (const float*)d_in[11];
    const float* b2b = (const float*)d_in[12];
    const float* W2c = (const float*)d_in[13];
    const float* b2c = (const float*)d_in[14];
    const float* Wx2 = (const float*)d_in[15];
    const float* bx2 = (const float*)d_in[16];

    char* wsb = (char*)d_ws;
    unsigned short* WP   = (unsigned short*)(wsb + OFF_WP);
    unsigned short* X1P  = (unsigned short*)(wsb + OFF_X1P);
    unsigned short* XMP  = (unsigned short*)(wsb + OFF_XMP);
    unsigned short* X2P  = (unsigned short*)(wsb + OFF_X2P);
    unsigned short* X3P  = (unsigned short*)(wsb + OFF_X3P);
    unsigned short* X4P  = (unsigned short*)(wsb + OFF_X4P);
    float*    c1    = (float*)(wsb + OFF_C1);
    unsigned* globE = (unsigned*)(wsb + OFF_GLOBE);
    float*    gbias = (float*)(wsb + OFF_GBIAS);
    float*    hacc1 = (float*)(wsb + OFF_HACC1);
    float*    hacc2 = (float*)(wsb + OFF_HACC2);
    char*     bar   = wsb + OFF_CNT;

    float* out0 = (float*)d_out;          // (2,1024,3)
    float* out1 = out0 + B * N1 * 3;      // (2,2048,3)
    float* out2 = out1 + B * N2 * 3;      // (2,2048,3) fine_points

    hipMemsetAsync(bar, 0, 4096, stream);   // zero barrier lines (capture-legal)

    k_mega<<<NBLK, 256, 0, stream>>>(
        z, W1a, b1a, W1b, b1b, W1c, b1c, Wx1, bx1,
        W2a, b2a, W2b, b2b, W2c, b2c, Wx2, bx2,
        WP, X1P, XMP, X2P, X3P, X4P,
        c1, globE, gbias, hacc1, hacc2,
        (float*)(wsb + OFF_GLOBE), bar,
        out0, out1, out2);
}

// Round 9
// 200.028 us; speedup vs baseline: 6.1613x; 1.9397x over previous
//
#include <hip/hip_runtime.h>
#include <math.h>

#define B 2
#define N1 1024
#define N2 2048
#define SLOPE 0.2f
#define QG 8         // queries per k_ball block

typedef short bf16x8 __attribute__((ext_vector_type(8)));
typedef float f32x4 __attribute__((ext_vector_type(4)));
typedef unsigned short u16x4 __attribute__((ext_vector_type(4)));
typedef unsigned short u16x8 __attribute__((ext_vector_type(8)));

__device__ __forceinline__ unsigned short f2bf(float x) {
    unsigned int u = __float_as_uint(x);
    unsigned int r = (u + 0x7fffu + ((u >> 16) & 1u)) >> 16;   // RNE
    return (unsigned short)r;
}
__device__ __forceinline__ float bf2f(unsigned short h) {
    return __uint_as_float(((unsigned int)h) << 16);
}
// order-preserving float<->u32 (for atomicMax)
__device__ __forceinline__ unsigned fenc(float f) {
    unsigned u = __float_as_uint(f);
    return (u & 0x80000000u) ? ~u : (u | 0x80000000u);
}
__device__ __forceinline__ float fdec(unsigned u) {
    unsigned b = (u & 0x80000000u) ? (u & 0x7FFFFFFFu) : ~u;
    return __uint_as_float(b);
}

// ---- ws byte offsets ----
#define OFF_WP     0
#define OFF_X1P    6291456
#define OFF_XMP    18874368
#define OFF_X2P    31457280
#define OFF_X3P    39845888
#define OFF_X4P    44040192
#define OFF_C1     48234496
#define OFF_GLOBE  48238592
#define OFF_GBIAS  48242688
#define OFF_HACC1  48246784   // [6144][4] f32
#define OFF_HACC2  48345088   // [4096][4] f32
#define ZERO_WORDS 43008      // globE..hacc2 end

// ---------------- prep: pack weights (float4-vectorized) + zero accs + c1 GEMV ----------------
// Packing: 1,572,864 elems, 4 per thread -> 1536 blocks. Rows are 512/1536 floats so a
// 4-wide chunk never crosses a row or region boundary; float4 load + u16x4 stores.
__global__ void k_prep(const float* __restrict__ W1b, const float* __restrict__ W1c,
                       const float* __restrict__ W2b, const float* __restrict__ W2c,
                       const float* __restrict__ W2a, unsigned short* __restrict__ wp,
                       const float* __restrict__ z, const float* __restrict__ W1a,
                       const float* __restrict__ b1a, float* __restrict__ c1,
                       float* __restrict__ zbase) {
    int bx = blockIdx.x, tid = threadIdx.x;
    if (bx < 1536) {
        int idx = bx * 1024 + tid * 4;        // base element index (4 consecutive k)
        const float* src; unsigned short* dst; int o, k, K, in_ld;
        bool need_lo;
        if (idx < 1048576) {
            int which = idx >> 18; int local = idx & 262143;
            K = 512; in_ld = 512;
            src = (which == 0) ? W1b : (which == 1) ? W1c : (which == 2) ? W2b : W2c;
            dst = wp + (long)which * 524288;
            o = local >> 9; k = local & 511;
            need_lo = (which < 2);   // only W1b/W1c (TERMS=3) read lo halves
        } else {
            int local = idx - 1048576;
            K = 1024; in_ld = 1536; src = W2a; dst = wp + 2097152;
            o = local >> 10; k = local & 1023;
            need_lo = false;         // TERMS=1 never reads lo
        }
        f32x4 v = *(const f32x4*)(const void*)(src + (long)o * in_ld + k);
        u16x4 hi, lo;
        #pragma unroll
        for (int q = 0; q < 4; ++q) {
            hi[q] = f2bf(v[q]);
            lo[q] = f2bf(v[q] - bf2f(hi[q]));
        }
        *(u16x4*)(void*)(dst + (long)o * 2 * K + k) = hi;
        if (need_lo)
            *(u16x4*)(void*)(dst + (long)o * 2 * K + K + k) = lo;
    } else if (bx < 1544) {
        for (int l = (bx - 1536) * 256 + tid; l < ZERO_WORDS; l += 2048) zbase[l] = 0.f;
    } else {
        int gid = (bx - 1544) * 4 + (tid >> 6);   // 0..1023
        int lane = tid & 63;
        int b = gid >> 9, o = gid & 511;
        float acc = 0.f;
        const float* wr = W1a + (long)o * 514;
        const float* zb = z + b * 512;
        for (int k = lane; k < 512; k += 64) acc += wr[k] * zb[k];
        #pragma unroll
        for (int off = 32; off > 0; off >>= 1) acc += __shfl_down(acc, off, 64);
        if (lane == 0) c1[gid] = acc + b1a[o];
    }
}

// ---------------- layer 1a: pointwise rank-2 update, emit packed [Xh|Xl] ----------------
__global__ void k_layer_a(const float* __restrict__ W1a, const float* __restrict__ c1,
                          unsigned short* __restrict__ X1) {
    int bx = blockIdx.x;
    int r = bx >> 1;                          // 0..6143, uniform per block
    int o = ((bx & 1) << 8) + threadIdx.x;    // 0..511
    int b, n, side;
    if (r < 2048) { b = r >> 10; n = r & 1023; side = 32; }
    else          { int r2 = r - 2048; b = r2 >> 11; n = r2 & 2047; side = 46; }
    int row, col;
    if (side == 32) { row = n >> 5; col = n & 31; }
    else            { row = n / 46; col = n - row * 46; }
    double inv = 1.0 / (double)(side - 1);
    float lx = (row == side - 1) ? 1.0f : (float)(row * inv);
    float ly = (col == side - 1) ? 1.0f : (float)(col * inv);
    float h = c1[b * 512 + o] + W1a[(long)o * 514 + 512] * lx + W1a[(long)o * 514 + 513] * ly;
    h = (h > 0.f) ? h : SLOPE * h;
    unsigned short hi = f2bf(h);
    X1[(long)r * 1024 + o] = hi;
    X1[(long)r * 1024 + 512 + o] = f2bf(h - bf2f(hi));
}

// ---------------- MFMA GEMM: TERMS=3 split-bf16, TERMS=1 plain bf16 ----------------
// Round-5 structure (best measured): TERMS=3 single 32KB buffer @3 blocks/CU,
// TERMS=1 double-buffered 2x16KB @4 blocks/CU.
template<int TERMS>
__global__ __launch_bounds__(256, (TERMS == 3) ? 3 : 4) void k_gemm(
    const unsigned short* __restrict__ Wp, int ldw,
    const unsigned short* __restrict__ Xp, int ldx,
    int K,
    const float* __restrict__ bias, int bias_div,
    unsigned short* __restrict__ Xn, int ldxn, int lo_off, int row_off, int pack_min,
    const float* __restrict__ Wx, float* __restrict__ hacc,
    unsigned* __restrict__ globE, int glob_min) {

    constexpr int NBUF  = (TERMS == 3) ? 1 : 2;
    constexpr int BUFSZ = (TERMS == 3) ? 32768 : 16384;   // per K-tile LDS footprint
    constexpr int XBASE = (TERMS == 3) ? 16384 : 8192;    // X-tile base within buffer
    __shared__ __align__(16) char sm[NBUF * BUFSZ];

    const int t = threadIdx.x;
    const int nb0 = blockIdx.x * 64;
    const int ob0 = blockIdx.y * 64;

    const unsigned short* gp[8];
    int lo_[8];
    #pragma unroll
    for (int p = 0; p < 8; ++p) {
        const int T = p >> 1;
        if (TERMS == 1 && (T == 1 || T == 3)) continue;
        int j2 = ((p & 1) << 8) + t;
        int r = j2 >> 3, cl = j2 & 7, cs = cl ^ (r & 7);
        gp[p] = (T < 2)
            ? (Wp + (long)(ob0 + r) * ldw + ((T == 1) ? K : 0) + cs * 8)
            : (Xp + (long)(nb0 + r) * ldx + ((T == 3) ? K : 0) + cs * 8);
        const int reg = (TERMS == 3) ? p : ((p < 2) ? p : p - 2);
        lo_[p] = reg * 4096 + t * 16;
    }

    const int lane = t & 63, w = t >> 6;
    const int wy = w >> 1, wx = w & 1;
    const int quad = lane >> 4, l15 = lane & 15;
    const int xm = l15 & 7;
    const int rowA = (wy * 32 + l15) * 128;
    const int rowB = (wx * 32 + l15) * 128;
    const int ca0 = (quad ^ xm) * 16;
    const int ca1 = ((quad + 4) ^ xm) * 16;

    f32x4 acc[2][2];
    #pragma unroll
    for (int i = 0; i < 2; ++i)
        #pragma unroll
        for (int j = 0; j < 2; ++j) { f32x4 zz = {0.f, 0.f, 0.f, 0.f}; acc[i][j] = zz; }

    auto stage = [&](int buf, int k0) {
        #pragma unroll
        for (int p = 0; p < 8; ++p) {
            const int T = p >> 1;
            if (TERMS == 1 && (T == 1 || T == 3)) continue;
            __builtin_amdgcn_global_load_lds(
                (const __attribute__((address_space(1))) void*)(const void*)(gp[p] + k0),
                (__attribute__((address_space(3))) void*)(void*)(sm + buf * BUFSZ + lo_[p]),
                16, 0, 0);
        }
    };

    auto compute = [&](int buf) {
        char* smb = sm + buf * BUFSZ;
        #pragma unroll
        for (int sub = 0; sub < 2; ++sub) {
            const int cb = (sub == 0) ? ca0 : ca1;
            bf16x8 ah[2], bh[2];
            #pragma unroll
            for (int i = 0; i < 2; ++i)
                ah[i] = *(const bf16x8*)(const void*)(smb + rowA + i * 2048 + cb);
            #pragma unroll
            for (int j = 0; j < 2; ++j)
                bh[j] = *(const bf16x8*)(const void*)(smb + XBASE + rowB + j * 2048 + cb);
            if (TERMS == 3) {
                bf16x8 al[2], bl[2];
                #pragma unroll
                for (int i = 0; i < 2; ++i)
                    al[i] = *(const bf16x8*)(const void*)(smb + 8192 + rowA + i * 2048 + cb);
                #pragma unroll
                for (int j = 0; j < 2; ++j)
                    bl[j] = *(const bf16x8*)(const void*)(smb + 24576 + rowB + j * 2048 + cb);
                #pragma unroll
                for (int i = 0; i < 2; ++i)
                    #pragma unroll
                    for (int j = 0; j < 2; ++j) {
                        acc[i][j] = __builtin_amdgcn_mfma_f32_16x16x32_bf16(ah[i], bh[j], acc[i][j], 0, 0, 0);
                        acc[i][j] = __builtin_amdgcn_mfma_f32_16x16x32_bf16(ah[i], bl[j], acc[i][j], 0, 0, 0);
                        acc[i][j] = __builtin_amdgcn_mfma_f32_16x16x32_bf16(al[i], bh[j], acc[i][j], 0, 0, 0);
                    }
            } else {
                #pragma unroll
                for (int i = 0; i < 2; ++i)
                    #pragma unroll
                    for (int j = 0; j < 2; ++j)
                        acc[i][j] = __builtin_amdgcn_mfma_f32_16x16x32_bf16(ah[i], bh[j], acc[i][j], 0, 0, 0);
            }
        }
    };

    if constexpr (TERMS == 3) {
        for (int k0 = 0; k0 < K; k0 += 64) {
            stage(0, k0);
            __syncthreads();
            compute(0);
            __syncthreads();
        }
    } else {
        stage(0, 0);
        __syncthreads();
        int cur = 0;
        for (int k0 = 64; k0 < K; k0 += 64) {
            stage(cur ^ 1, k0);
            compute(cur);
            __syncthreads();
            cur ^= 1;
        }
        compute(cur);
    }

    // ---- epilogue ----
    float val[2][2][4];
    #pragma unroll
    for (int j = 0; j < 2; ++j) {
        int n = nb0 + wx * 32 + j * 16 + l15;
        int bidx0 = (bias_div >= (1 << 29)) ? 0 : (n / bias_div) * 512;
        #pragma unroll
        for (int i = 0; i < 2; ++i) {
            int ob = ob0 + wy * 32 + i * 16 + quad * 4;
            #pragma unroll
            for (int r = 0; r < 4; ++r) {
                float x = acc[i][j][r] + bias[bidx0 + ob + r];
                val[i][j][r] = (x > 0.f) ? x : SLOPE * x;
            }
        }
        if (Xn && n >= pack_min) {
            long nl = n - row_off;
            #pragma unroll
            for (int i = 0; i < 2; ++i) {
                int ob = ob0 + wy * 32 + i * 16 + quad * 4;
                u16x4 h4;
                #pragma unroll
                for (int r = 0; r < 4; ++r) h4[r] = f2bf(val[i][j][r]);
                *(u16x4*)(void*)(Xn + nl * ldxn + ob) = h4;
                if (lo_off) {
                    u16x4 l4;
                    #pragma unroll
                    for (int r = 0; r < 4; ++r) l4[r] = f2bf(val[i][j][r] - bf2f(h4[r]));
                    *(u16x4*)(void*)(Xn + nl * ldxn + lo_off + ob) = l4;
                }
            }
        }
    }

    if (hacc) {
        __syncthreads();
        float* smh = (float*)sm;                     // [64][4]
        unsigned* smg = (unsigned*)(sm + 1024);      // [64]
        if (t < 256) smh[t] = 0.f;
        if (t < 64) smg[t] = 0u;
        __syncthreads();
        float wxv[3][2][4];
        #pragma unroll
        for (int ch = 0; ch < 3; ++ch)
            #pragma unroll
            for (int i = 0; i < 2; ++i)
                #pragma unroll
                for (int r = 0; r < 4; ++r)
                    wxv[ch][i][r] = Wx[ch * 512 + ob0 + wy * 32 + i * 16 + quad * 4 + r];
        #pragma unroll
        for (int j = 0; j < 2; ++j) {
            int nl = wx * 32 + j * 16 + l15;
            float p0 = 0.f, p1 = 0.f, p2 = 0.f;
            #pragma unroll
            for (int i = 0; i < 2; ++i)
                #pragma unroll
                for (int r = 0; r < 4; ++r) {
                    float v = val[i][j][r];
                    p0 += v * wxv[0][i][r];
                    p1 += v * wxv[1][i][r];
                    p2 += v * wxv[2][i][r];
                }
            atomicAdd(&smh[nl * 4 + 0], p0);
            atomicAdd(&smh[nl * 4 + 1], p1);
            atomicAdd(&smh[nl * 4 + 2], p2);
        }
        if (globE && nb0 >= glob_min) {
            #pragma unroll
            for (int i = 0; i < 2; ++i)
                #pragma unroll
                for (int r = 0; r < 4; ++r) {
                    float mx = fmaxf(val[i][0][r], val[i][1][r]);
                    atomicMax(&smg[wy * 32 + i * 16 + quad * 4 + r], fenc(mx));
                }
        }
        __syncthreads();
        if (t < 64) {
            atomicAdd(&hacc[(long)(nb0 + t) * 4 + 0], smh[t * 4 + 0]);
            atomicAdd(&hacc[(long)(nb0 + t) * 4 + 1], smh[t * 4 + 1]);
            atomicAdd(&hacc[(long)(nb0 + t) * 4 + 2], smh[t * 4 + 2]);
            if (globE && nb0 >= glob_min) {
                int b = (nb0 - glob_min) >> 11;
                atomicMax(&globE[b * 512 + ob0 + t], smg[t]);
            }
        }
    }
}

// ---------------- finalize stage-1: sigmoid heads + gbias GEMV ----------------
__global__ void k_finalize(const float* __restrict__ bx1, const float* __restrict__ hacc1,
                           float* __restrict__ out0, float* __restrict__ out2,
                           const float* __restrict__ W2a, const float* __restrict__ b2a,
                           const unsigned* __restrict__ globE, float* __restrict__ gbias) {
    int bx = blockIdx.x, tid = threadIdx.x;
    if (bx < 24) {
        int r = bx * 256 + tid;    // 0..6143
        float* dst = (r < 2048) ? (out0 + (long)r * 3) : (out2 + (long)(r - 2048) * 3);
        #pragma unroll
        for (int ch = 0; ch < 3; ++ch) {
            float a = hacc1[(long)r * 4 + ch] + bx1[ch];
            dst[ch] = 1.f / (1.f + expf(-a)) - 0.5f;
        }
    } else {
        int gid = (bx - 24) * 4 + (tid >> 6);   // 0..1023
        int lane = tid & 63;
        int b = gid >> 9, o = gid & 511;
        float acc = 0.f;
        const float* wr = W2a + (long)o * 1536 + 1024;
        for (int k = lane; k < 512; k += 64) acc += wr[k] * fdec(globE[b * 512 + k]);
        #pragma unroll
        for (int off = 32; off > 0; off >>= 1) acc += __shfl_down(acc, off, 64);
        if (lane == 0) gbias[gid] = acc + b2a[o];
    }
}

// ---------------- ball query, 8 queries/block: shared scan + union gather-max ----------------
__global__ __launch_bounds__(256) void k_ball(const float* __restrict__ fine,
                                              unsigned short* __restrict__ X2P) {
    int i0 = blockIdx.x * QG, b = blockIdx.y;
    int tid = threadIdx.x, lane = tid & 63, wv = tid >> 6;
    __shared__ float pts[N2 * 3];              // 24576 B
    __shared__ unsigned char mark[N2];         // 2048 B
    __shared__ int wcnt[4][QG];                // 128 B
    __shared__ int ulist[512];                 // 2048 B
    __shared__ int ucnt;

    const float* fb = fine + (long)b * N2 * 3;
    for (int l = tid; l < N2 * 3; l += 256) pts[l] = fb[l];
    *(int*)(void*)&mark[tid * 8] = 0;
    *(int*)(void*)&mark[tid * 8 + 4] = 0;
    if (tid == 0) ucnt = 0;
    __syncthreads();

    float cx[QG], cy[QG], cz[QG], sqc[QG];
    #pragma unroll
    for (int g = 0; g < QG; ++g) {
        cx[g] = pts[(i0 + g) * 3 + 0];
        cy[g] = pts[(i0 + g) * 3 + 1];
        cz[g] = pts[(i0 + g) * 3 + 2];
        sqc[g] = __fadd_rn(__fadd_rn(__fmul_rn(cx[g], cx[g]), __fmul_rn(cy[g], cy[g])),
                           __fmul_rn(cz[g], cz[g]));
    }

    int cnt[QG];
    #pragma unroll
    for (int g = 0; g < QG; ++g) cnt[g] = 0;

    for (int it = 0; it < N2 / 256; ++it) {
        int j = it * 256 + tid;
        float xj = pts[j * 3 + 0], yj = pts[j * 3 + 1], zj = pts[j * 3 + 2];
        float sqj = __fadd_rn(__fadd_rn(__fmul_rn(xj, xj), __fmul_rn(yj, yj)), __fmul_rn(zj, zj));
        unsigned long long bm[QG];
        #pragma unroll
        for (int g = 0; g < QG; ++g) {
            float dot = __fadd_rn(__fadd_rn(__fmul_rn(cx[g], xj), __fmul_rn(cy[g], yj)),
                                  __fmul_rn(cz[g], zj));
            float d2 = __fsub_rn(__fadd_rn(sqc[g], sqj), __fmul_rn(2.0f, dot));
            bm[g] = __ballot(d2 < 0.01f);
        }
        if (lane < QG) wcnt[wv][lane] = __popcll(bm[lane]);
        __syncthreads();
        unsigned mybits = 0;
        #pragma unroll
        for (int g = 0; g < QG; ++g) {
            int base = cnt[g];
            #pragma unroll
            for (int q = 0; q < 3; ++q) { if (q < wv) base += wcnt[q][g]; }
            int rank = base + __popcll(bm[g] & ((1ull << lane) - 1ull));
            if (((bm[g] >> lane) & 1ull) && rank < 64) mybits |= 1u << g;
            cnt[g] += wcnt[0][g] + wcnt[1][g] + wcnt[2][g] + wcnt[3][g];
        }
        mark[j] = (unsigned char)mybits;
        bool done = true;
        #pragma unroll
        for (int g = 0; g < QG; ++g) done = done && (cnt[g] >= 64);
        __syncthreads();                 // wcnt reuse + mark visibility
        if (done) break;                 // uniform (cnt identical across threads)
    }

    // union list (order irrelevant for max)
    for (int it = 0; it < N2 / 256; ++it) {
        int j = it * 256 + tid;
        unsigned mk = mark[j];
        if (mk) { int r = atomicAdd(&ucnt, 1); ulist[r] = j | ((int)mk << 16); }
    }
    __syncthreads();
    int nu = __builtin_amdgcn_readfirstlane(ucnt);

    // gather: every thread walks every union row, owns channels 2*tid, 2*tid+1
    const unsigned short* hb = X2P + (long)b * N2 * 1024;
    float a0[QG], a1[QG];
    #pragma unroll
    for (int g = 0; g < QG; ++g) { a0[g] = -1e30f; a1[g] = -1e30f; }

    auto apply = [&](unsigned mk, unsigned v) {
        float f0 = bf2f((unsigned short)(v & 0xFFFFu));
        float f1 = bf2f((unsigned short)(v >> 16));
        #pragma unroll
        for (int g = 0; g < QG; ++g) {
            if (mk & (1u << g)) {   // block-uniform scalar branch
                a0[g] = fmaxf(a0[g], f0);
                a1[g] = fmaxf(a1[g], f1);
            }
        }
    };

    int u = 0;
    for (; u + 4 <= nu; u += 4) {
        int e0 = __builtin_amdgcn_readfirstlane(ulist[u + 0]);
        int e1 = __builtin_amdgcn_readfirstlane(ulist[u + 1]);
        int e2 = __builtin_amdgcn_readfirstlane(ulist[u + 2]);
        int e3 = __builtin_amdgcn_readfirstlane(ulist[u + 3]);
        unsigned v0 = *(const unsigned*)(const void*)(hb + (long)(e0 & 0xFFFF) * 1024 + tid * 2);
        unsigned v1 = *(const unsigned*)(const void*)(hb + (long)(e1 & 0xFFFF) * 1024 + tid * 2);
        unsigned v2 = *(const unsigned*)(const void*)(hb + (long)(e2 & 0xFFFF) * 1024 + tid * 2);
        unsigned v3 = *(const unsigned*)(const void*)(hb + (long)(e3 & 0xFFFF) * 1024 + tid * 2);
        apply(((unsigned)e0) >> 16, v0);
        apply(((unsigned)e1) >> 16, v1);
        apply(((unsigned)e2) >> 16, v2);
        apply(((unsigned)e3) >> 16, v3);
    }
    for (; u < nu; ++u) {
        int e = __builtin_amdgcn_readfirstlane(ulist[u]);
        unsigned v = *(const unsigned*)(const void*)(hb + (long)(e & 0xFFFF) * 1024 + tid * 2);
        apply(((unsigned)e) >> 16, v);
    }

    #pragma unroll
    for (int g = 0; g < QG; ++g) {
        unsigned short* orow = X2P + (long)(b * N2 + i0 + g) * 1024;
        unsigned w2 = (unsigned)(__float_as_uint(a0[g]) >> 16)
                    | ((__float_as_uint(a1[g]) >> 16) << 16);   // exact: bf16-valued
        *(unsigned*)(void*)(orow + 512 + tid * 2) = w2;
    }
}

// ---------------- finalize stage-2: out1 = fine + 0.1*(sigmoid-0.5) ----------------
__global__ void k_final2(const float* __restrict__ bx2, const float* __restrict__ hacc2,
                         const float* __restrict__ fine, float* __restrict__ out1) {
    int r = blockIdx.x * 256 + threadIdx.x;   // 0..4095
    #pragma unroll
    for (int ch = 0; ch < 3; ++ch) {
        float a = hacc2[(long)r * 4 + ch] + bx2[ch];
        out1[(long)r * 3 + ch] = fine[(long)r * 3 + ch] + 0.1f * (1.f / (1.f + expf(-a)) - 0.5f);
    }
}

// ---------------- launch ----------------
extern "C" void kernel_launch(void* const* d_in, const int* in_sizes, int n_in,
                              void* d_out, int out_size, void* d_ws, size_t ws_size,
                              hipStream_t stream) {
    const float* z   = (const float*)d_in[0];
    const float* W1a = (const float*)d_in[1];
    const float* b1a = (const float*)d_in[2];
    const float* W1b = (const float*)d_in[3];
    const float* b1b = (const float*)d_in[4];
    const float* W1c = (const float*)d_in[5];
    const float* b1c = (const float*)d_in[6];
    const float* Wx1 = (const float*)d_in[7];
    const float* bx1 = (const float*)d_in[8];
    const float* W2a = (const float*)d_in[9];
    const float* b2a = (const float*)d_in[10];
    const float* W2b = (const float*)d_in[11];
    const float* b2b = (const float*)d_in[12];
    const float* W2c = (const float*)d_in[13];
    const float* b2c = (const float*)d_in[14];
    const float* Wx2 = (const float*)d_in[15];
    const float* bx2 = (const float*)d_in[16];

    char* wsb = (char*)d_ws;
    unsigned short* WP   = (unsigned short*)(wsb + OFF_WP);
    unsigned short* X1P  = (unsigned short*)(wsb + OFF_X1P);   // [6144][1024] hi|lo
    unsigned short* XMP  = (unsigned short*)(wsb + OFF_XMP);   // [6144][1024] hi|lo
    unsigned short* X2P  = (unsigned short*)(wsb + OFF_X2P);   // [4096][1024] h3|local (hi)
    unsigned short* X3P  = (unsigned short*)(wsb + OFF_X3P);   // [4096][512] hi
    unsigned short* X4P  = (unsigned short*)(wsb + OFF_X4P);   // [4096][512] hi
    float*    c1    = (float*)(wsb + OFF_C1);
    unsigned* globE = (unsigned*)(wsb + OFF_GLOBE);
    float*    gbias = (float*)(wsb + OFF_GBIAS);
    float*    hacc1 = (float*)(wsb + OFF_HACC1);
    float*    hacc2 = (float*)(wsb + OFF_HACC2);

    unsigned short* WP1b = WP;
    unsigned short* WP1c = WP + 524288;
    unsigned short* WP2b = WP + 1048576;
    unsigned short* WP2c = WP + 1572864;
    unsigned short* WP2a = WP + 2097152;

    float* out0 = (float*)d_out;          // (2,1024,3)
    float* out1 = out0 + B * N1 * 3;      // (2,2048,3)
    float* out2 = out1 + B * N2 * 3;      // (2,2048,3) fine_points
    float* fine = out2;

    const int BIG = 1 << 30;

    k_prep<<<1800, 256, 0, stream>>>(W1b, W1c, W2b, W2c, W2a, WP, z, W1a, b1a, c1,
                                     (float*)(wsb + OFF_GLOBE));
    k_layer_a<<<12288, 256, 0, stream>>>(W1a, c1, X1P);

    // stage-1 MLP (split-bf16, N1+N2 fused: 6144 rows)
    k_gemm<3><<<dim3(96, 8), 256, 0, stream>>>(WP1b, 1024, X1P, 1024, 512, b1b, BIG,
                                               XMP, 1024, 512, 0, 0,
                                               nullptr, nullptr, nullptr, 0);
    k_gemm<3><<<dim3(96, 8), 256, 0, stream>>>(WP1c, 1024, XMP, 1024, 512, b1c, BIG,
                                               X2P, 1024, 0, 2048, 2048,
                                               Wx1, hacc1, globE, 2048);
    k_finalize<<<280, 256, 0, stream>>>(bx1, hacc1, out0, out2, W2a, b2a, globE, gbias);
    k_ball<<<dim3(N2 / QG, B), 256, 0, stream>>>(fine, X2P);

    // stage-2 MLP (plain bf16, 4096 rows)
    k_gemm<1><<<dim3(64, 8), 256, 0, stream>>>(WP2a, 2048, X2P, 1024, 1024, gbias, 2048,
                                               X3P, 512, 0, 0, 0,
                                               nullptr, nullptr, nullptr, 0);
    k_gemm<1><<<dim3(64, 8), 256, 0, stream>>>(WP2b, 1024, X3P, 512, 512, b2b, BIG,
                                               X4P, 512, 0, 0, 0,
                                               nullptr, nullptr, nullptr, 0);
    k_gemm<1><<<dim3(64, 8), 256, 0, stream>>>(WP2c, 1024, X4P, 512, 512, b2c, BIG,
                                               nullptr, 0, 0, 0, 0,
                                               Wx2, hacc2, nullptr, 0);
    k_final2<<<16, 256, 0, stream>>>(bx2, hacc2, fine, out1);
}